// Round 1
// baseline (421.996 us; speedup 1.0000x reference)
//
#include <hip/hip_runtime.h>
#include <math.h>

#define NPTS 256
#define FDIM 512
#define H1   300
#define H1P  320   // padded stride for a-part rows
#define H2   100

// ---- workspace layout (float offsets) ----
#define OFF_APART  0
#define APART_SZ   (4*2*NPTS*H1P)            // a1,a2,b1,b2 each [B][N][H1P]
#define OFF_KW2T   (OFF_APART + APART_SZ)    // kw2 transposed [H1][H2]
#define OFF_R      (OFF_KW2T + 30720)        // R_est [B][N][N]
#define OFF_PNA    (OFF_R + 131072)
#define OFF_PNB    (OFF_PNA + 262144)
#define OFF_WEIGHT (OFF_PNB + 262144)
#define OFF_MLAT   (OFF_WEIGHT + 512)        // per b: Pbar[3], Minv[9] (16-pad)
#define OFF_SUMSQ  (OFF_MLAT + 32)           // [B][256]

// ============ Kernel A: a-part GEMMs ============
// out[jb][n][h] = sum_f kw1[h][colOff+f] * emb[b][f][n]
// jb = j*2+b ; j: 0=a1(W1a,A) 1=a2(W1b,A) 2=b1(W1a,B) 3=b2(W1b,B)
__global__ __launch_bounds__(256) void k_apart(
    const float* __restrict__ embA, const float* __restrict__ embB,
    const float* __restrict__ kw1, float* __restrict__ apart)
{
    const int tile = blockIdx.x;        // 0..19 : 4 n-tiles x 5 h-tiles
    const int nt = tile & 3, ht = tile >> 2;
    const int jb = blockIdx.y;          // 0..7
    const int j = jb >> 1, b = jb & 1;
    const int n0 = nt * 64, h0 = ht * 64;
    const float* emb = ((j < 2) ? embA : embB) + b * FDIM * NPTS;
    const int colOff = (j & 1) ? FDIM : 0;

    __shared__ float sE[32][64];
    __shared__ float sW[64][33];
    const int tid = threadIdx.x;
    const int tx = tid & 15, ty = tid >> 4;

    float acc[4][4];
    #pragma unroll
    for (int i = 0; i < 4; ++i)
        { acc[i][0]=0.f; acc[i][1]=0.f; acc[i][2]=0.f; acc[i][3]=0.f; }

    for (int kt = 0; kt < 16; ++kt) {
        const int f0 = kt * 32;
        #pragma unroll
        for (int i = 0; i < 8; ++i) {
            int idx = i * 256 + tid;
            int ff = idx >> 6, nn = idx & 63;
            sE[ff][nn] = emb[(f0 + ff) * NPTS + n0 + nn];
        }
        #pragma unroll
        for (int i = 0; i < 8; ++i) {
            int idx = i * 256 + tid;
            int hh = idx >> 5, ffw = idx & 31;
            int h = h0 + hh;
            sW[hh][ffw] = (h < H1) ? kw1[h * (2*FDIM) + colOff + f0 + ffw] : 0.f;
        }
        __syncthreads();
        #pragma unroll 8
        for (int ff = 0; ff < 32; ++ff) {
            const float4 ev = *reinterpret_cast<const float4*>(&sE[ff][ty * 4]);
            #pragma unroll
            for (int jh = 0; jh < 4; ++jh) {
                float wv = sW[tx * 4 + jh][ff];
                acc[0][jh] = fmaf(ev.x, wv, acc[0][jh]);
                acc[1][jh] = fmaf(ev.y, wv, acc[1][jh]);
                acc[2][jh] = fmaf(ev.z, wv, acc[2][jh]);
                acc[3][jh] = fmaf(ev.w, wv, acc[3][jh]);
            }
        }
        __syncthreads();
    }
    float* outb = apart + (size_t)jb * NPTS * H1P;
    #pragma unroll
    for (int i = 0; i < 4; ++i) {
        int n = n0 + ty * 4 + i;
        float4 v; v.x = acc[i][0]; v.y = acc[i][1]; v.z = acc[i][2]; v.w = acc[i][3];
        *reinterpret_cast<float4*>(&outb[n * H1P + h0 + tx * 4]) = v;
    }
}

// ============ transpose kw2 -> kw2t[h][g] ============
__global__ void k_kw2t(const float* __restrict__ kw2, float* __restrict__ kw2t)
{
    int idx = blockIdx.x * 256 + threadIdx.x;
    if (idx < H2 * H1) {
        int g = idx / H1, h = idx - g * H1;
        kw2t[h * H2 + g] = kw2[idx];
    }
}

// ============ Kernel B: fused pair tail ============
// thread = (pair p, tail t). tail0: tail(a1[n]+b2[m]+kb1); tail1: tail(a2[n]+b1[m]+kb1)
// R[b][n][m] = softplus(0.5*(v1+v2))
__global__ __launch_bounds__(512, 2) void k_pair(
    const float* __restrict__ apart, const float* __restrict__ kw2t,
    const float* __restrict__ kb1, const float* __restrict__ kb2,
    const float* __restrict__ kw3, const float* __restrict__ kb3,
    float* __restrict__ R)
{
    const int mt = blockIdx.x, nt = blockIdx.y, b = blockIdx.z;
    const int n0 = nt * 16, m0 = mt * 16;
    __shared__ float sP[4][16][H1];     // a1,a2,b1,b2 tiles
    __shared__ float kb1_sh[H1];
    __shared__ float kb2_sh[H2];
    __shared__ float kw3_sh[H2];
    __shared__ float sV[256];
    const int tid = threadIdx.x;

    for (int idx = tid; idx < 4 * 16 * 75; idx += 512) {
        int jj = idx / 1200;
        int rem = idx - jj * 1200;
        int row = rem / 75;
        int q = rem - row * 75;
        int base = (jj < 2) ? n0 : m0;
        const float4 v = *reinterpret_cast<const float4*>(
            &apart[(size_t)((jj * 2 + b) * NPTS + base + row) * H1P + q * 4]);
        *reinterpret_cast<float4*>(&sP[jj][row][q * 4]) = v;
    }
    if (tid < H1) kb1_sh[tid] = kb1[tid];
    if (tid < H2) { kb2_sh[tid] = kb2[tid]; kw3_sh[tid] = kw3[tid]; }
    __syncthreads();

    const int p = tid & 255;
    const int tail = tid >> 8;          // wave-uniform (waves 0-3 vs 4-7)
    const int tn = p >> 4, tm = p & 15;
    const float* pA = &sP[tail][tn][0];      // tail0: a1, tail1: a2
    const float* pB = &sP[3 - tail][tm][0];  // tail0: b2, tail1: b1

    float acc[H2];
    #pragma unroll
    for (int g = 0; g < H2; ++g) acc[g] = 0.f;

    for (int h = 0; h < H1; ++h) {
        float rp = pA[h] + pB[h] + kb1_sh[h];
        rp = fmaxf(rp, 0.f);
        const float* wr = kw2t + h * H2;   // uniform address -> s_load
        #pragma unroll
        for (int g = 0; g < H2; ++g) acc[g] = fmaf(rp, wr[g], acc[g]);
    }

    float v = kb3[0];
    #pragma unroll
    for (int g = 0; g < H2; ++g)
        v = fmaf(kw3_sh[g], fmaxf(acc[g] + kb2_sh[g], 0.f), v);

    if (tail) sV[p] = v;
    __syncthreads();
    if (!tail) {
        float s = 0.5f * (v + sV[p]);
        float sp = fmaxf(s, 0.f) + log1pf(expf(-fabsf(s)));   // stable softplus
        R[(size_t)(b * NPTS + n0 + tn) * NPTS + m0 + tm] = sp;
    }
}

// ============ PointNet layer ============
template <int CIN, bool RELUBIAS>
__global__ __launch_bounds__(256) void k_pn(
    const float* __restrict__ x, const float* __restrict__ w,
    const float* __restrict__ bias, float* __restrict__ out)
{
    const int o = blockIdx.x, b = blockIdx.y, n = threadIdx.x;
    const int O = gridDim.x;
    const float* xb = x + (size_t)b * CIN * NPTS + n;
    const float* wr = w + (size_t)o * CIN;
    float acc = 0.f;
    #pragma unroll 16
    for (int c = 0; c < CIN; ++c)
        acc = fmaf(wr[c], xb[c * NPTS], acc);
    if (RELUBIAS) acc = fmaxf(acc + bias[o], 0.f);
    out[((size_t)b * O + o) * NPTS + n] = acc;
}

// ============ multilateration setup: Pbar, Minv, |P_B|^2 ============
__global__ __launch_bounds__(256) void k_mlat_setup(
    const float* __restrict__ anchor_pts, float* __restrict__ mlat,
    float* __restrict__ sumsq)
{
    const int b = blockIdx.x, n = threadIdx.x;
    const float px = anchor_pts[b * 768 + n];
    const float py = anchor_pts[b * 768 + 256 + n];
    const float pz = anchor_pts[b * 768 + 512 + n];
    __shared__ float red[256];
    float sums[9];
    float vals[9] = {px, py, pz, px*px, px*py, px*pz, py*py, py*pz, pz*pz};
    #pragma unroll
    for (int k = 0; k < 9; ++k) {
        red[n] = vals[k]; __syncthreads();
        for (int s = 128; s > 0; s >>= 1) {
            if (n < s) red[n] += red[n + s];
            __syncthreads();
        }
        sums[k] = red[0]; __syncthreads();
    }
    sumsq[b * 256 + n] = px*px + py*py + pz*pz;
    if (n == 0) {
        const float inv = 1.f / 256.f;
        float mx = sums[0]*inv, my = sums[1]*inv, mz = sums[2]*inv;
        float a_ = sums[3]*inv - mx*mx;   // Mxx
        float b_ = sums[4]*inv - mx*my;   // Mxy
        float c_ = sums[5]*inv - mx*mz;   // Mxz
        float d_ = sums[6]*inv - my*my;   // Myy
        float e_ = sums[7]*inv - my*mz;   // Myz
        float f_ = sums[8]*inv - mz*mz;   // Mzz
        float c00 = d_*f_ - e_*e_;
        float c01 = c_*e_ - b_*f_;
        float c02 = b_*e_ - c_*d_;
        float det = a_*c00 + b_*c01 + c_*c02;
        float id = 1.f / det;
        float* mb = mlat + b * 16;
        mb[0] = mx; mb[1] = my; mb[2] = mz;
        mb[3] = c00*id;              mb[4] = c01*id;              mb[5] = c02*id;
        mb[6] = c01*id;              mb[7] = (a_*f_ - c_*c_)*id;  mb[8] = (b_*c_ - a_*e_)*id;
        mb[9] = c02*id;              mb[10]= (b_*c_ - a_*e_)*id;  mb[11]= (a_*d_ - b_*b_)*id;
    }
}

// ============ solve + epilogue: flow/corr/full_flow ============
__global__ __launch_bounds__(256) void k_solve_out(
    const float* __restrict__ R, const float* __restrict__ mlat,
    const float* __restrict__ sumsq, const float* __restrict__ anchor_pts,
    const float* __restrict__ action_pts, const float* __restrict__ weight,
    float* __restrict__ out)
{
    const int b = blockIdx.x, a = threadIdx.x;
    const float* mb = mlat + b * 16;
    const float Pbx = mb[0], Pby = mb[1], Pbz = mb[2];
    float v0 = 0.f, v1 = 0.f, v2 = 0.f;
    const float* Rrow = R + (size_t)(b * NPTS + a) * NPTS;
    const float* sq = sumsq + b * NPTS;
    const float* ap = anchor_pts + b * 768;
    #pragma unroll 4
    for (int n = 0; n < NPTS; ++n) {
        float Rv = Rrow[n];
        float cc = sq[n] - Rv * Rv;
        v0 = fmaf(cc, ap[n]       - Pbx, v0);
        v1 = fmaf(cc, ap[256 + n] - Pby, v1);
        v2 = fmaf(cc, ap[512 + n] - Pbz, v2);
    }
    const float sc = 0.5f / 256.f;
    v0 *= sc; v1 *= sc; v2 *= sc;
    float p0 = mb[3]*v0 + mb[4]*v1 + mb[5]*v2;
    float p1 = mb[6]*v0 + mb[7]*v1 + mb[8]*v2;
    float p2 = mb[9]*v0 + mb[10]*v1 + mb[11]*v2;
    float f0 = p0 - action_pts[b * 768 + a];
    float f1 = p1 - action_pts[b * 768 + 256 + a];
    float f2 = p2 - action_pts[b * 768 + 512 + a];
    float wv = weight[b * NPTS + a];
    // full_flow [B][4][256]
    out[b * 1024 + a]        = f0;
    out[b * 1024 + 256 + a]  = f1;
    out[b * 1024 + 512 + a]  = f2;
    out[b * 1024 + 768 + a]  = wv;
    // flow [B][3][256] @2048
    out[2048 + b * 768 + a]        = f0;
    out[2048 + b * 768 + 256 + a]  = f1;
    out[2048 + b * 768 + 512 + a]  = f2;
    // corr_points [B][3][256] @3584
    out[3584 + b * 768 + a]        = p0;
    out[3584 + b * 768 + 256 + a]  = p1;
    out[3584 + b * 768 + 512 + a]  = p2;
}

extern "C" void kernel_launch(void* const* d_in, const int* in_sizes, int n_in,
                              void* d_out, int out_size, void* d_ws, size_t ws_size,
                              hipStream_t stream)
{
    const float* embA       = (const float*)d_in[0];
    const float* embB       = (const float*)d_in[1];
    const float* action_pts = (const float*)d_in[2];
    const float* anchor_pts = (const float*)d_in[3];
    const float* kw1 = (const float*)d_in[4];
    const float* kb1 = (const float*)d_in[5];
    const float* kw2 = (const float*)d_in[6];
    const float* kb2 = (const float*)d_in[7];
    const float* kw3 = (const float*)d_in[8];
    const float* kb3 = (const float*)d_in[9];
    const float* pw0 = (const float*)d_in[10];
    const float* pb0 = (const float*)d_in[11];
    const float* pw1 = (const float*)d_in[12];
    const float* pb1 = (const float*)d_in[13];
    const float* pw2 = (const float*)d_in[14];
    const float* pb2 = (const float*)d_in[15];
    const float* pw3 = (const float*)d_in[16];
    const float* pb3 = (const float*)d_in[17];
    const float* pw4 = (const float*)d_in[18];
    const float* pb4 = (const float*)d_in[19];
    const float* headw = (const float*)d_in[20];
    float* ws  = (float*)d_ws;
    float* out = (float*)d_out;

    float* apart = ws + OFF_APART;
    float* kw2t  = ws + OFF_KW2T;
    float* R     = ws + OFF_R;
    float* pnA   = ws + OFF_PNA;
    float* pnB   = ws + OFF_PNB;
    float* wgt   = ws + OFF_WEIGHT;
    float* mlat  = ws + OFF_MLAT;
    float* sumsq = ws + OFF_SUMSQ;

    hipLaunchKernelGGL(k_apart, dim3(20, 8), dim3(256), 0, stream, embA, embB, kw1, apart);
    hipLaunchKernelGGL(k_kw2t, dim3(118), dim3(256), 0, stream, kw2, kw2t);
    hipLaunchKernelGGL((k_pn<512, true>),  dim3(64, 2),  dim3(256), 0, stream, embA, pw0, pb0, pnA);
    hipLaunchKernelGGL((k_pn<64, true>),   dim3(64, 2),  dim3(256), 0, stream, pnA, pw1, pb1, pnB);
    hipLaunchKernelGGL((k_pn<64, true>),   dim3(64, 2),  dim3(256), 0, stream, pnB, pw2, pb2, pnA);
    hipLaunchKernelGGL((k_pn<64, true>),   dim3(128, 2), dim3(256), 0, stream, pnA, pw3, pb3, pnB);
    hipLaunchKernelGGL((k_pn<128, true>),  dim3(512, 2), dim3(256), 0, stream, pnB, pw4, pb4, pnA);
    hipLaunchKernelGGL((k_pn<512, false>), dim3(1, 2),   dim3(256), 0, stream, pnA, headw, nullptr, wgt);
    hipLaunchKernelGGL(k_pair, dim3(16, 16, 2), dim3(512), 0, stream,
                       apart, kw2t, kb1, kb2, kw3, kb3, R);
    hipLaunchKernelGGL(k_mlat_setup, dim3(2), dim3(256), 0, stream, anchor_pts, mlat, sumsq);
    hipLaunchKernelGGL(k_solve_out, dim3(2), dim3(256), 0, stream,
                       R, mlat, sumsq, anchor_pts, action_pts, wgt, out);
}

// Round 2
// 301.678 us; speedup vs baseline: 1.3988x; 1.3988x over previous
//
#include <hip/hip_runtime.h>
#include <math.h>

#define NPTS 256
#define FDIM 512
#define H1   300
#define KP   320    // padded K (H1 -> 320)
#define H2   100
#define NP   112    // padded N (H2 -> 112)

typedef _Float16 half8  __attribute__((ext_vector_type(8)));
typedef _Float16 half4v __attribute__((ext_vector_type(4)));
typedef _Float16 half2v __attribute__((ext_vector_type(2)));
typedef float    floatx4 __attribute__((ext_vector_type(4)));

// ---- workspace layout (byte offsets) ----
#define OFF_AP    0            // ap f16 [4 j][2 b][256 n][320 k] : 1,310,720 B
#define OFF_KW2F  1310720      // kw2 f16 padded [112][320]       :    71,680 B
#define OFF_PNW   1382400      // pointnet weights f16 transposed :   230,400 B
#define OFF_R     1612800      // R fp32 [2][256][256]            :   524,288 B
#define OFF_WGT   2137088      // weight fp32 [2][256]            :     2,048 B

// pn weight sub-offsets (f16 elements from OFF_PNW)
// w0t [512][64] @0 ; w1t [64][64] @32768 ; w2t [64][64] @36864 ;
// w3t [64][128] @40960 ; w4t [128][512] @49152 ; headw [512] @114688

// ============ prep: kw2 pad+cast, pointnet weight transpose+cast ============
__global__ __launch_bounds__(256) void k_prep(
    const float* __restrict__ kw2,
    const float* __restrict__ pw0, const float* __restrict__ pw1,
    const float* __restrict__ pw2, const float* __restrict__ pw3,
    const float* __restrict__ pw4, const float* __restrict__ headw,
    _Float16* __restrict__ kw2f, _Float16* __restrict__ pnw)
{
    int idx = blockIdx.x * 256 + threadIdx.x;
    if (idx < 35840) {                       // kw2f [112][320]
        int g = idx / 320, h = idx - g * 320;
        kw2f[idx] = (_Float16)((g < H2 && h < H1) ? kw2[g * H1 + h] : 0.f);
        return;
    }
    int i = idx - 35840;
    if (i < 32768) {                          // w0t [512][64]
        int c = i >> 6, o = i & 63;
        pnw[i] = (_Float16)pw0[o * 512 + c];
        return;
    }
    i -= 32768;
    if (i < 4096) {                           // w1t [64][64]
        int c = i >> 6, o = i & 63;
        pnw[32768 + i] = (_Float16)pw1[o * 64 + c];
        return;
    }
    i -= 4096;
    if (i < 4096) {                           // w2t [64][64]
        int c = i >> 6, o = i & 63;
        pnw[36864 + i] = (_Float16)pw2[o * 64 + c];
        return;
    }
    i -= 4096;
    if (i < 8192) {                           // w3t [64][128]
        int c = i >> 7, o = i & 127;
        pnw[40960 + i] = (_Float16)pw3[o * 64 + c];
        return;
    }
    i -= 8192;
    if (i < 65536) {                          // w4t [128][512]
        int c = i >> 9, o = i & 511;
        pnw[49152 + i] = (_Float16)pw4[o * 128 + c];
        return;
    }
    i -= 65536;
    if (i < 512) pnw[114688 + i] = (_Float16)headw[i];
}

// ============ Kernel A: first-layer GEMMs -> f16, kb1 folded into a1/a2 ============
// ap[j*2+b][n][k] f16, k-stride 320 (zeros for k>=300)
// j: 0=a1(W1a@PhiA+kb1) 1=a2(W1b@PhiA+kb1) 2=b1(W1a@PhiB) 3=b2(W1b@PhiB)
__global__ __launch_bounds__(256) void k_apart(
    const float* __restrict__ embA, const float* __restrict__ embB,
    const float* __restrict__ kw1, const float* __restrict__ kb1,
    _Float16* __restrict__ ap)
{
    const int tile = blockIdx.x;        // 4 n-tiles x 5 h-tiles
    const int nt = tile & 3, ht = tile >> 2;
    const int jb = blockIdx.y;          // 0..7
    const int j = jb >> 1, b = jb & 1;
    const int n0 = nt * 64, h0 = ht * 64;
    const float* emb = ((j < 2) ? embA : embB) + b * FDIM * NPTS;
    const int colOff = (j & 1) ? FDIM : 0;
    const bool addb = (j < 2);

    __shared__ float sE[32][64];
    __shared__ float sW[64][33];
    const int tid = threadIdx.x;
    const int tx = tid & 15, ty = tid >> 4;

    float acc[4][4];
    #pragma unroll
    for (int i = 0; i < 4; ++i)
        { acc[i][0]=0.f; acc[i][1]=0.f; acc[i][2]=0.f; acc[i][3]=0.f; }

    for (int kt = 0; kt < 16; ++kt) {
        const int f0 = kt * 32;
        #pragma unroll
        for (int i = 0; i < 8; ++i) {
            int idx = i * 256 + tid;
            int ff = idx >> 6, nn = idx & 63;
            sE[ff][nn] = emb[(f0 + ff) * NPTS + n0 + nn];
        }
        #pragma unroll
        for (int i = 0; i < 8; ++i) {
            int idx = i * 256 + tid;
            int hh = idx >> 5, ffw = idx & 31;
            int h = h0 + hh;
            sW[hh][ffw] = (h < H1) ? kw1[h * (2*FDIM) + colOff + f0 + ffw] : 0.f;
        }
        __syncthreads();
        #pragma unroll 8
        for (int ff = 0; ff < 32; ++ff) {
            const float4 ev = *reinterpret_cast<const float4*>(&sE[ff][ty * 4]);
            #pragma unroll
            for (int jh = 0; jh < 4; ++jh) {
                float wv = sW[tx * 4 + jh][ff];
                acc[0][jh] = fmaf(ev.x, wv, acc[0][jh]);
                acc[1][jh] = fmaf(ev.y, wv, acc[1][jh]);
                acc[2][jh] = fmaf(ev.z, wv, acc[2][jh]);
                acc[3][jh] = fmaf(ev.w, wv, acc[3][jh]);
            }
        }
        __syncthreads();
    }
    float bv[4];
    #pragma unroll
    for (int jh = 0; jh < 4; ++jh) {
        int h = h0 + tx * 4 + jh;
        bv[jh] = (addb && h < H1) ? kb1[h] : 0.f;
    }
    _Float16* outb = ap + (size_t)jb * NPTS * KP;
    #pragma unroll
    for (int i = 0; i < 4; ++i) {
        int n = n0 + ty * 4 + i;
        half4v hv;
        #pragma unroll
        for (int jh = 0; jh < 4; ++jh)
            hv[jh] = (_Float16)(acc[i][jh] + bv[jh]);
        *reinterpret_cast<half4v*>(&outb[(size_t)n * KP + h0 + tx * 4]) = hv;
    }
}

// ============ Kernel B: fused pair tail via f16 MFMA ============
// Block: 256 rows = 2 tails x 8 n x 16 m pairs; N=112 (kw2 padded), K=320.
// row r = tail*128 + n_l*16 + m_l ; M-tile = r>>4 ; wave w owns tiles 4w..4w+3.
#define ASTR 328   // a/b tile row stride (f16), 2-way max on staging reads
#define PSTR 40    // pre/B row stride (f16), 16B-aligned rows; slot-swizzled
__global__ __launch_bounds__(256, 2) void k_pair(
    const _Float16* __restrict__ ap, const _Float16* __restrict__ kw2f,
    const float* __restrict__ kb2, const float* __restrict__ kw3,
    const float* __restrict__ kb3, float* __restrict__ R)
{
    const int mt = blockIdx.x, nt = blockIdx.y, b = blockIdx.z;
    const int m0 = mt * 16, n0 = nt * 8;
    __shared__ __align__(16) _Float16 sAB[48 * ASTR];  // 0-7 a1, 8-15 a2, 16-31 b1, 32-47 b2
    __shared__ __align__(16) _Float16 sPre[256 * PSTR];
    __shared__ __align__(16) _Float16 sB[NP * PSTR];
    __shared__ float sV[256];
    const int tid = threadIdx.x;
    const int wave = tid >> 6, lane = tid & 63;
    const int l15 = lane & 15, quad = lane >> 4;

    // ---- load a/b tiles: 48 rows x 320 f16 = 1920 x half8 ----
    for (int idx = tid; idx < 1920; idx += 256) {
        int row = idx / 40;
        int col = (idx - row * 40) * 8;
        int j, gn;
        if      (row < 8)  { j = 0; gn = n0 + row; }
        else if (row < 16) { j = 1; gn = n0 + row - 8; }
        else if (row < 32) { j = 2; gn = m0 + row - 16; }
        else               { j = 3; gn = m0 + row - 32; }
        half8 v = *reinterpret_cast<const half8*>(
            &ap[(size_t)((j * 2 + b) * NPTS + gn) * KP + col]);
        *reinterpret_cast<half8*>(&sAB[row * ASTR + col]) = v;
    }

    floatx4 acc[4][7];
    #pragma unroll
    for (int i = 0; i < 4; ++i)
        #pragma unroll
        for (int jj = 0; jj < 7; ++jj)
            acc[i][jj] = (floatx4){0.f, 0.f, 0.f, 0.f};

    // staging row for this thread
    const int sr = tid;                         // 0..255
    const int s_tail = sr >> 7, s_n = (sr >> 4) & 7, s_m = sr & 15;
    const _Float16* arow = &sAB[(size_t)((s_tail ? 8 : 0) + s_n) * ASTR];    // a1 / a2
    const _Float16* brow = &sAB[(size_t)((s_tail ? 16 : 32) + s_m) * ASTR];  // b1 / b2
    const int rsw = sr + (sr >> 3);
    const int brw = (tid >> 1) + ((tid >> 1) >> 3);  // B staging swizzle base

    __syncthreads();   // sAB ready

    for (int kc = 0; kc < 10; ++kc) {
        const int k0 = kc * 32;
        // ---- stage pre = relu(a + b), slot-swizzled into A-frag layout ----
        #pragma unroll
        for (int ko = 0; ko < 4; ++ko) {
            half8 av = *reinterpret_cast<const half8*>(&arow[k0 + ko * 8]);
            half8 bv = *reinterpret_cast<const half8*>(&brow[k0 + ko * 8]);
            half8 rv;
            #pragma unroll
            for (int e = 0; e < 8; ++e) {
                _Float16 x = av[e] + bv[e];
                rv[e] = x > (_Float16)0 ? x : (_Float16)0;
            }
            int ps = (ko + rsw) & 3;
            *reinterpret_cast<half8*>(&sPre[sr * PSTR + ps * 8]) = rv;
        }
        // ---- stage B chunk [112][32] from kw2f ----
        if (tid < 224) {
            int row = tid >> 1;
            #pragma unroll
            for (int q = 0; q < 2; ++q) {
                int sl = (tid & 1) * 2 + q;
                half8 v = *reinterpret_cast<const half8*>(
                    &kw2f[(size_t)row * KP + k0 + sl * 8]);
                int ps = (sl + brw) & 3;
                *reinterpret_cast<half8*>(&sB[row * PSTR + ps * 8]) = v;
            }
        }
        __syncthreads();
        // ---- MFMA: wave w, 4 M-tiles x 7 N-tiles ----
        half8 af[4];
        #pragma unroll
        for (int i = 0; i < 4; ++i) {
            int row = (wave * 4 + i) * 16 + l15;
            int ps = (quad + row + (row >> 3)) & 3;
            af[i] = *reinterpret_cast<const half8*>(&sPre[row * PSTR + ps * 8]);
        }
        #pragma unroll
        for (int jj = 0; jj < 7; ++jj) {
            int row = jj * 16 + l15;
            int ps = (quad + row + (row >> 3)) & 3;
            half8 bf = *reinterpret_cast<const half8*>(&sB[row * PSTR + ps * 8]);
            #pragma unroll
            for (int i = 0; i < 4; ++i)
                acc[i][jj] = __builtin_amdgcn_mfma_f32_16x16x32_f16(af[i], bf, acc[i][jj], 0, 0, 0);
        }
        __syncthreads();
    }

    // ---- epilogue: bias+relu on layer2, dot with kw3, reduce over g ----
    float kw3v[7], kb2v[7];
    #pragma unroll
    for (int jj = 0; jj < 7; ++jj) {
        int g = jj * 16 + l15;
        kw3v[jj] = (g < H2) ? kw3[g] : 0.f;
        kb2v[jj] = (g < H2) ? kb2[g] : 0.f;
    }
    #pragma unroll
    for (int i = 0; i < 4; ++i) {
        float rv0 = 0.f, rv1 = 0.f, rv2 = 0.f, rv3 = 0.f;
        #pragma unroll
        for (int jj = 0; jj < 7; ++jj) {
            float w3 = kw3v[jj], b2 = kb2v[jj];
            rv0 = fmaf(w3, fmaxf(acc[i][jj][0] + b2, 0.f), rv0);
            rv1 = fmaf(w3, fmaxf(acc[i][jj][1] + b2, 0.f), rv1);
            rv2 = fmaf(w3, fmaxf(acc[i][jj][2] + b2, 0.f), rv2);
            rv3 = fmaf(w3, fmaxf(acc[i][jj][3] + b2, 0.f), rv3);
        }
        #pragma unroll
        for (int m = 1; m < 16; m <<= 1) {
            rv0 += __shfl_xor(rv0, m, 64);
            rv1 += __shfl_xor(rv1, m, 64);
            rv2 += __shfl_xor(rv2, m, 64);
            rv3 += __shfl_xor(rv3, m, 64);
        }
        if (l15 == 0) {
            int base = (wave * 4 + i) * 16 + quad * 4;
            sV[base + 0] = rv0; sV[base + 1] = rv1;
            sV[base + 2] = rv2; sV[base + 3] = rv3;
        }
    }
    __syncthreads();
    if (tid < 128) {
        float s = 0.5f * (sV[tid] + sV[128 + tid]) + kb3[0];
        float sp = fmaxf(s, 0.f) + log1pf(expf(-fabsf(s)));
        int n_l = tid >> 4, m_l = tid & 15;
        R[(size_t)(b * NPTS + n0 + n_l) * NPTS + m0 + m_l] = sp;
    }
}

// ============ fused PointNet (all 6 layers) ============
// grid (32, 2): block = 8 points; threads: p = t>>5, ol = t&31
__global__ __launch_bounds__(256) void k_pn_fused(
    const float* __restrict__ emb, const _Float16* __restrict__ pnw,
    const float* __restrict__ pb0, const float* __restrict__ pb1,
    const float* __restrict__ pb2, const float* __restrict__ pb3,
    const float* __restrict__ pb4, float* __restrict__ wgt)
{
    const int b = blockIdx.y, n0 = blockIdx.x * 8;
    const _Float16* w0t = pnw;            // [512][64]
    const _Float16* w1t = pnw + 32768;    // [64][64]
    const _Float16* w2t = pnw + 36864;    // [64][64]
    const _Float16* w3t = pnw + 40960;    // [64][128]
    const _Float16* w4t = pnw + 49152;    // [128][512]
    const _Float16* hw  = pnw + 114688;   // [512]
    __shared__ float xs[512][8];
    __shared__ float hA[64][8];
    __shared__ float hB[64][8];
    __shared__ float hC[128][8];
    const int t = threadIdx.x;
    for (int i = t; i < 4096; i += 256) {
        int c = i >> 3, p = i & 7;
        xs[c][p] = emb[((size_t)b * 512 + c) * 256 + n0 + p];
    }
    __syncthreads();
    const int p = t >> 5, ol = t & 31;
    {   // L0: 512 -> 64
        float a0 = 0.f, a1 = 0.f;
        const _Float16* wp = w0t + 2 * ol;
        #pragma unroll 8
        for (int c = 0; c < 512; ++c) {
            float xv = xs[c][p];
            half2v wv = *reinterpret_cast<const half2v*>(wp + c * 64);
            a0 = fmaf(xv, (float)wv.x, a0);
            a1 = fmaf(xv, (float)wv.y, a1);
        }
        hA[2 * ol][p]     = fmaxf(a0 + pb0[2 * ol], 0.f);
        hA[2 * ol + 1][p] = fmaxf(a1 + pb0[2 * ol + 1], 0.f);
    }
    __syncthreads();
    {   // L1: 64 -> 64
        float a0 = 0.f, a1 = 0.f;
        const _Float16* wp = w1t + 2 * ol;
        #pragma unroll 8
        for (int c = 0; c < 64; ++c) {
            float xv = hA[c][p];
            half2v wv = *reinterpret_cast<const half2v*>(wp + c * 64);
            a0 = fmaf(xv, (float)wv.x, a0);
            a1 = fmaf(xv, (float)wv.y, a1);
        }
        hB[2 * ol][p]     = fmaxf(a0 + pb1[2 * ol], 0.f);
        hB[2 * ol + 1][p] = fmaxf(a1 + pb1[2 * ol + 1], 0.f);
    }
    __syncthreads();
    {   // L2: 64 -> 64
        float a0 = 0.f, a1 = 0.f;
        const _Float16* wp = w2t + 2 * ol;
        #pragma unroll 8
        for (int c = 0; c < 64; ++c) {
            float xv = hB[c][p];
            half2v wv = *reinterpret_cast<const half2v*>(wp + c * 64);
            a0 = fmaf(xv, (float)wv.x, a0);
            a1 = fmaf(xv, (float)wv.y, a1);
        }
        hA[2 * ol][p]     = fmaxf(a0 + pb2[2 * ol], 0.f);
        hA[2 * ol + 1][p] = fmaxf(a1 + pb2[2 * ol + 1], 0.f);
    }
    __syncthreads();
    {   // L3: 64 -> 128
        float a0 = 0.f, a1 = 0.f, a2 = 0.f, a3 = 0.f;
        const _Float16* wp = w3t + 4 * ol;
        #pragma unroll 8
        for (int c = 0; c < 64; ++c) {
            float xv = hA[c][p];
            half4v wv = *reinterpret_cast<const half4v*>(wp + c * 128);
            a0 = fmaf(xv, (float)wv[0], a0);
            a1 = fmaf(xv, (float)wv[1], a1);
            a2 = fmaf(xv, (float)wv[2], a2);
            a3 = fmaf(xv, (float)wv[3], a3);
        }
        hC[4 * ol + 0][p] = fmaxf(a0 + pb3[4 * ol + 0], 0.f);
        hC[4 * ol + 1][p] = fmaxf(a1 + pb3[4 * ol + 1], 0.f);
        hC[4 * ol + 2][p] = fmaxf(a2 + pb3[4 * ol + 2], 0.f);
        hC[4 * ol + 3][p] = fmaxf(a3 + pb3[4 * ol + 3], 0.f);
    }
    __syncthreads();
    // L4 (128 -> 512) + head, fused
    float s = 0.f;
    for (int k = 0; k < 16; ++k) {
        int o = ol + (k << 5);
        float a0 = 0.f, a1 = 0.f;
        #pragma unroll 4
        for (int c = 0; c < 128; c += 2) {
            a0 = fmaf(hC[c][p],     (float)w4t[c * 512 + o],       a0);
            a1 = fmaf(hC[c + 1][p], (float)w4t[(c + 1) * 512 + o], a1);
        }
        s += (float)hw[o] * fmaxf(a0 + a1 + pb4[o], 0.f);
    }
    #pragma unroll
    for (int m = 1; m < 32; m <<= 1) s += __shfl_xor(s, m, 64);
    if (ol == 0) wgt[(size_t)b * 256 + n0 + p] = s;
}

// ============ fused multilateration setup + solve + epilogue ============
// grid (8, 2): block = 32 action rows; redundant per-block mlat setup (cheap)
__global__ __launch_bounds__(256) void k_solve(
    const float* __restrict__ R, const float* __restrict__ anchor_pts,
    const float* __restrict__ action_pts, const float* __restrict__ weight,
    float* __restrict__ out)
{
    const int a0 = blockIdx.x * 32, b = blockIdx.y;
    __shared__ float apx[256], apy[256], apz[256], sq[256];
    __shared__ float red[256];
    __shared__ float mb[12];
    const int t = threadIdx.x;
    const float px = anchor_pts[b * 768 + t];
    const float py = anchor_pts[b * 768 + 256 + t];
    const float pz = anchor_pts[b * 768 + 512 + t];
    apx[t] = px; apy[t] = py; apz[t] = pz;
    sq[t] = px * px + py * py + pz * pz;
    float sums[9];
    {
        float vals[9] = {px, py, pz, px*px, px*py, px*pz, py*py, py*pz, pz*pz};
        #pragma unroll
        for (int k = 0; k < 9; ++k) {
            red[t] = vals[k]; __syncthreads();
            for (int s = 128; s > 0; s >>= 1) {
                if (t < s) red[t] += red[t + s];
                __syncthreads();
            }
            sums[k] = red[0]; __syncthreads();
        }
    }
    if (t == 0) {
        const float inv = 1.f / 256.f;
        float mx = sums[0]*inv, my = sums[1]*inv, mz = sums[2]*inv;
        float a_ = sums[3]*inv - mx*mx;
        float b_ = sums[4]*inv - mx*my;
        float c_ = sums[5]*inv - mx*mz;
        float d_ = sums[6]*inv - my*my;
        float e_ = sums[7]*inv - my*mz;
        float f_ = sums[8]*inv - mz*mz;
        float c00 = d_*f_ - e_*e_;
        float c01 = c_*e_ - b_*f_;
        float c02 = b_*e_ - c_*d_;
        float det = a_*c00 + b_*c01 + c_*c02;
        float id = 1.f / det;
        mb[0] = mx; mb[1] = my; mb[2] = mz;
        mb[3] = c00*id;  mb[4] = c01*id;             mb[5] = c02*id;
        mb[6] = c01*id;  mb[7] = (a_*f_ - c_*c_)*id; mb[8] = (b_*c_ - a_*e_)*id;
        mb[9] = c02*id;  mb[10] = (b_*c_ - a_*e_)*id; mb[11] = (a_*d_ - b_*b_)*id;
    }
    __syncthreads();
    const int ar = a0 + (t >> 3), l8 = t & 7;
    const float Pbx = mb[0], Pby = mb[1], Pbz = mb[2];
    const float* Rrow = R + (size_t)(b * NPTS + ar) * NPTS;
    float v0 = 0.f, v1 = 0.f, v2 = 0.f;
    #pragma unroll 4
    for (int k = 0; k < 32; ++k) {
        int n = l8 + (k << 3);
        float Rv = Rrow[n];
        float cc = sq[n] - Rv * Rv;
        v0 = fmaf(cc, apx[n] - Pbx, v0);
        v1 = fmaf(cc, apy[n] - Pby, v1);
        v2 = fmaf(cc, apz[n] - Pbz, v2);
    }
    #pragma unroll
    for (int m = 1; m < 8; m <<= 1) {
        v0 += __shfl_xor(v0, m, 64);
        v1 += __shfl_xor(v1, m, 64);
        v2 += __shfl_xor(v2, m, 64);
    }
    if (l8 == 0) {
        const float sc = 0.5f / 256.f;
        v0 *= sc; v1 *= sc; v2 *= sc;
        float p0 = mb[3]*v0 + mb[4]*v1 + mb[5]*v2;
        float p1 = mb[6]*v0 + mb[7]*v1 + mb[8]*v2;
        float p2 = mb[9]*v0 + mb[10]*v1 + mb[11]*v2;
        float f0 = p0 - action_pts[b * 768 + ar];
        float f1 = p1 - action_pts[b * 768 + 256 + ar];
        float f2 = p2 - action_pts[b * 768 + 512 + ar];
        float wv = weight[b * NPTS + ar];
        out[b * 1024 + ar]              = f0;
        out[b * 1024 + 256 + ar]        = f1;
        out[b * 1024 + 512 + ar]        = f2;
        out[b * 1024 + 768 + ar]        = wv;
        out[2048 + b * 768 + ar]        = f0;
        out[2048 + b * 768 + 256 + ar]  = f1;
        out[2048 + b * 768 + 512 + ar]  = f2;
        out[3584 + b * 768 + ar]        = p0;
        out[3584 + b * 768 + 256 + ar]  = p1;
        out[3584 + b * 768 + 512 + ar]  = p2;
    }
}

extern "C" void kernel_launch(void* const* d_in, const int* in_sizes, int n_in,
                              void* d_out, int out_size, void* d_ws, size_t ws_size,
                              hipStream_t stream)
{
    const float* embA       = (const float*)d_in[0];
    const float* embB       = (const float*)d_in[1];
    const float* action_pts = (const float*)d_in[2];
    const float* anchor_pts = (const float*)d_in[3];
    const float* kw1 = (const float*)d_in[4];
    const float* kb1 = (const float*)d_in[5];
    const float* kw2 = (const float*)d_in[6];
    const float* kb2 = (const float*)d_in[7];
    const float* kw3 = (const float*)d_in[8];
    const float* kb3 = (const float*)d_in[9];
    const float* pw0 = (const float*)d_in[10];
    const float* pb0 = (const float*)d_in[11];
    const float* pw1 = (const float*)d_in[12];
    const float* pb1 = (const float*)d_in[13];
    const float* pw2 = (const float*)d_in[14];
    const float* pb2 = (const float*)d_in[15];
    const float* pw3 = (const float*)d_in[16];
    const float* pb3 = (const float*)d_in[17];
    const float* pw4 = (const float*)d_in[18];
    const float* pb4 = (const float*)d_in[19];
    const float* headw = (const float*)d_in[20];
    char* wsb = (char*)d_ws;
    float* out = (float*)d_out;

    _Float16* ap    = (_Float16*)(wsb + OFF_AP);
    _Float16* kw2f  = (_Float16*)(wsb + OFF_KW2F);
    _Float16* pnw   = (_Float16*)(wsb + OFF_PNW);
    float*    R     = (float*)(wsb + OFF_R);
    float*    wgt   = (float*)(wsb + OFF_WGT);

    hipLaunchKernelGGL(k_prep, dim3(590), dim3(256), 0, stream,
                       kw2, pw0, pw1, pw2, pw3, pw4, headw, kw2f, pnw);
    hipLaunchKernelGGL(k_apart, dim3(20, 8), dim3(256), 0, stream,
                       embA, embB, kw1, kb1, ap);
    hipLaunchKernelGGL(k_pn_fused, dim3(32, 2), dim3(256), 0, stream,
                       embA, pnw, pb0, pb1, pb2, pb3, pb4, wgt);
    hipLaunchKernelGGL(k_pair, dim3(16, 32, 2), dim3(256), 0, stream,
                       ap, kw2f, kb2, kw3, kb3, R);
    hipLaunchKernelGGL(k_solve, dim3(8, 2), dim3(256), 0, stream,
                       R, anchor_pts, action_pts, wgt, out);
}

// Round 3
// 198.455 us; speedup vs baseline: 2.1264x; 1.5201x over previous
//
#include <hip/hip_runtime.h>
#include <math.h>

#define NPTS 256
#define FDIM 512
#define H1   300
#define KP   320    // padded K (H1 -> 320)
#define H2   100
#define NP   112    // padded N (H2 -> 112)

typedef _Float16 half8  __attribute__((ext_vector_type(8)));
typedef float    floatx4 __attribute__((ext_vector_type(4)));

// ---- workspace layout (byte offsets) ----
#define OFF_AP    0          // ap f16 [4 j][2 b][256 n][320 k]   : 1,310,720 B
#define OFF_KW2F  1310720    // kw2 f16 padded [112][320]         :    71,680 B
#define OFF_PNW   1382400    // pointnet weights f16 frag order   :   229,376 B
#define OFF_KW1F  1611776    // kw1 f16 frag order [2][16][20][512]: 655,360 B
#define OFF_R     2267136    // R fp32 [2][256][256]              :   524,288 B
#define OFF_WGT   2791424    // weight fp32 [2][256]              :     2,048 B

// pnw sub-offsets (f16 elements):
// w0frag [s16][nt4][64][8] @0      (32768)   src pw0 [64][512]
// w1frag [s2][nt4][64][8]  @32768  (4096)    src pw1 [64][64]
// w2frag [s2][nt4][64][8]  @36864  (4096)    src pw2 [64][64]
// w3frag [s2][nt8][64][8]  @40960  (8192)    src pw3 [128][64]
// w4frag [s4][nt32][64][8] @49152  (65536)   src pw4 [512][128]

// ============ prep: cast/pad kw2; arrange pn + kw1 weights in B-frag order ============
// B-frag (mfma_f32_16x16x32_f16): lane l holds B[k][n] with n = nt*16 + (l&15),
// k = s*32 + (l>>4)*8 + e, e=0..7 contiguous -> one dwordx4 per lane at runtime.
__global__ __launch_bounds__(256) void k_prep(
    const float* __restrict__ kw2, const float* __restrict__ kw1,
    const float* __restrict__ pw0, const float* __restrict__ pw1,
    const float* __restrict__ pw2, const float* __restrict__ pw3,
    const float* __restrict__ pw4,
    _Float16* __restrict__ kw2f, _Float16* __restrict__ pnw,
    _Float16* __restrict__ kw1f)
{
    int idx = blockIdx.x * 256 + threadIdx.x;
    if (idx < 35840) {                       // kw2f [112][320]
        int g = idx / 320, h = idx - g * 320;
        kw2f[idx] = (_Float16)((g < H2 && h < H1) ? kw2[g * H1 + h] : 0.f);
        return;
    }
    int i = idx - 35840;
    if (i < 114688) {                        // pointnet frags
        const float* src; int K, NT, off;
        if      (i < 32768) { src = pw0; K = 512; NT = 4;  off = 0; }
        else if (i < 36864) { src = pw1; K = 64;  NT = 4;  off = 32768; }
        else if (i < 40960) { src = pw2; K = 64;  NT = 4;  off = 36864; }
        else if (i < 49152) { src = pw3; K = 64;  NT = 8;  off = 40960; }
        else                { src = pw4; K = 128; NT = 32; off = 49152; }
        int li = i - off;
        int e = li & 7, l = (li >> 3) & 63, r = li >> 9;
        int nt = r % NT, s = r / NT;
        int o = nt * 16 + (l & 15);
        int c = s * 32 + ((l >> 4) << 3) + e;
        pnw[i] = (_Float16)src[o * K + c];
        return;
    }
    i -= 114688;
    if (i < 327680) {                        // kw1 frags [half][s16][nt20][64][8]
        int e = i & 7, l = (i >> 3) & 63, r = i >> 9;     // r 0..639
        int nt = r % 20, s = (r / 20) & 15, half = r / 320;
        int h = nt * 16 + (l & 15);
        int c = s * 32 + ((l >> 4) << 3) + e;
        kw1f[i] = (_Float16)((h < H1) ? kw1[h * (2 * FDIM) + half * FDIM + c] : 0.f);
    }
}

// ============ Kernel A: first-layer GEMMs via MFMA, kb1 folded into a1/a2 ============
// grid (16 ntiles, 8 jb), block 64 (1 wave = 16 points x all 320 h).
// ap[j*2+b][n][h] f16 (zeros for h>=300).
__global__ __launch_bounds__(64) void k_apart(
    const float* __restrict__ embA, const float* __restrict__ embB,
    const _Float16* __restrict__ kw1f, const float* __restrict__ kb1,
    _Float16* __restrict__ ap)
{
    const int ntile = blockIdx.x, jb = blockIdx.y;
    const int j = jb >> 1, b = jb & 1;
    const int n0 = ntile * 16;
    const int lane = threadIdx.x, l15 = lane & 15, quad = lane >> 4;
    const float* xb = ((j < 2) ? embA : embB) + b * FDIM * NPTS + n0 + l15;
    const _Float16* wf = kw1f + (size_t)(j & 1) * 163840;

    floatx4 acc[20];
    #pragma unroll
    for (int nt = 0; nt < 20; ++nt) acc[nt] = (floatx4){0.f, 0.f, 0.f, 0.f};

    for (int s = 0; s < 16; ++s) {
        const int cb = s * 32 + quad * 8;
        half8 af;
        #pragma unroll
        for (int e = 0; e < 8; ++e) af[e] = (_Float16)xb[(cb + e) * NPTS];
        const _Float16* wrow = wf + (size_t)s * 20 * 512 + lane * 8;
        #pragma unroll
        for (int nt = 0; nt < 20; ++nt) {
            half8 bf = *reinterpret_cast<const half8*>(wrow + nt * 512);
            acc[nt] = __builtin_amdgcn_mfma_f32_16x16x32_f16(af, bf, acc[nt], 0, 0, 0);
        }
    }
    const bool addb = (j < 2);
    _Float16* apb = ap + (size_t)jb * NPTS * KP;
    #pragma unroll
    for (int nt = 0; nt < 20; ++nt) {
        int h = nt * 16 + l15;
        float bv = (addb && h < H1) ? kb1[h] : 0.f;
        #pragma unroll
        for (int r = 0; r < 4; ++r) {
            int n = n0 + quad * 4 + r;
            apb[(size_t)n * KP + h] = (_Float16)(acc[nt][r] + bv);
        }
    }
}

// ============ Kernel B: fused pair tail via f16 MFMA (unchanged from R2) ============
#define ASTR 328
#define PSTR 40
__global__ __launch_bounds__(256, 2) void k_pair(
    const _Float16* __restrict__ ap, const _Float16* __restrict__ kw2f,
    const float* __restrict__ kb2, const float* __restrict__ kw3,
    const float* __restrict__ kb3, float* __restrict__ R)
{
    const int mt = blockIdx.x, nt = blockIdx.y, b = blockIdx.z;
    const int m0 = mt * 16, n0 = nt * 8;
    __shared__ __align__(16) _Float16 sAB[48 * ASTR];
    __shared__ __align__(16) _Float16 sPre[256 * PSTR];
    __shared__ __align__(16) _Float16 sB[NP * PSTR];
    __shared__ float sV[256];
    const int tid = threadIdx.x;
    const int wave = tid >> 6, lane = tid & 63;
    const int l15 = lane & 15, quad = lane >> 4;

    for (int idx = tid; idx < 1920; idx += 256) {
        int row = idx / 40;
        int col = (idx - row * 40) * 8;
        int j, gn;
        if      (row < 8)  { j = 0; gn = n0 + row; }
        else if (row < 16) { j = 1; gn = n0 + row - 8; }
        else if (row < 32) { j = 2; gn = m0 + row - 16; }
        else               { j = 3; gn = m0 + row - 32; }
        half8 v = *reinterpret_cast<const half8*>(
            &ap[(size_t)((j * 2 + b) * NPTS + gn) * KP + col]);
        *reinterpret_cast<half8*>(&sAB[row * ASTR + col]) = v;
    }

    floatx4 acc[4][7];
    #pragma unroll
    for (int i = 0; i < 4; ++i)
        #pragma unroll
        for (int jj = 0; jj < 7; ++jj)
            acc[i][jj] = (floatx4){0.f, 0.f, 0.f, 0.f};

    const int sr = tid;
    const int s_tail = sr >> 7, s_n = (sr >> 4) & 7, s_m = sr & 15;
    const _Float16* arow = &sAB[(size_t)((s_tail ? 8 : 0) + s_n) * ASTR];
    const _Float16* brow = &sAB[(size_t)((s_tail ? 16 : 32) + s_m) * ASTR];
    const int rsw = sr + (sr >> 3);
    const int brw = (tid >> 1) + ((tid >> 1) >> 3);

    __syncthreads();

    for (int kc = 0; kc < 10; ++kc) {
        const int k0 = kc * 32;
        #pragma unroll
        for (int ko = 0; ko < 4; ++ko) {
            half8 av = *reinterpret_cast<const half8*>(&arow[k0 + ko * 8]);
            half8 bv = *reinterpret_cast<const half8*>(&brow[k0 + ko * 8]);
            half8 rv;
            #pragma unroll
            for (int e = 0; e < 8; ++e) {
                _Float16 x = av[e] + bv[e];
                rv[e] = x > (_Float16)0 ? x : (_Float16)0;
            }
            int ps = (ko + rsw) & 3;
            *reinterpret_cast<half8*>(&sPre[sr * PSTR + ps * 8]) = rv;
        }
        if (tid < 224) {
            int row = tid >> 1;
            #pragma unroll
            for (int q = 0; q < 2; ++q) {
                int sl = (tid & 1) * 2 + q;
                half8 v = *reinterpret_cast<const half8*>(
                    &kw2f[(size_t)row * KP + k0 + sl * 8]);
                int ps = (sl + brw) & 3;
                *reinterpret_cast<half8*>(&sB[row * PSTR + ps * 8]) = v;
            }
        }
        __syncthreads();
        half8 af[4];
        #pragma unroll
        for (int i = 0; i < 4; ++i) {
            int row = (wave * 4 + i) * 16 + l15;
            int ps = (quad + row + (row >> 3)) & 3;
            af[i] = *reinterpret_cast<const half8*>(&sPre[row * PSTR + ps * 8]);
        }
        #pragma unroll
        for (int jj = 0; jj < 7; ++jj) {
            int row = jj * 16 + l15;
            int ps = (quad + row + (row >> 3)) & 3;
            half8 bf = *reinterpret_cast<const half8*>(&sB[row * PSTR + ps * 8]);
            #pragma unroll
            for (int i = 0; i < 4; ++i)
                acc[i][jj] = __builtin_amdgcn_mfma_f32_16x16x32_f16(af[i], bf, acc[i][jj], 0, 0, 0);
        }
        __syncthreads();
    }

    float kw3v[7], kb2v[7];
    #pragma unroll
    for (int jj = 0; jj < 7; ++jj) {
        int g = jj * 16 + l15;
        kw3v[jj] = (g < H2) ? kw3[g] : 0.f;
        kb2v[jj] = (g < H2) ? kb2[g] : 0.f;
    }
    #pragma unroll
    for (int i = 0; i < 4; ++i) {
        float rv0 = 0.f, rv1 = 0.f, rv2 = 0.f, rv3 = 0.f;
        #pragma unroll
        for (int jj = 0; jj < 7; ++jj) {
            float w3 = kw3v[jj], b2 = kb2v[jj];
            rv0 = fmaf(w3, fmaxf(acc[i][jj][0] + b2, 0.f), rv0);
            rv1 = fmaf(w3, fmaxf(acc[i][jj][1] + b2, 0.f), rv1);
            rv2 = fmaf(w3, fmaxf(acc[i][jj][2] + b2, 0.f), rv2);
            rv3 = fmaf(w3, fmaxf(acc[i][jj][3] + b2, 0.f), rv3);
        }
        #pragma unroll
        for (int m = 1; m < 16; m <<= 1) {
            rv0 += __shfl_xor(rv0, m, 64);
            rv1 += __shfl_xor(rv1, m, 64);
            rv2 += __shfl_xor(rv2, m, 64);
            rv3 += __shfl_xor(rv3, m, 64);
        }
        if (l15 == 0) {
            int base = (wave * 4 + i) * 16 + quad * 4;
            sV[base + 0] = rv0; sV[base + 1] = rv1;
            sV[base + 2] = rv2; sV[base + 3] = rv3;
        }
    }
    __syncthreads();
    if (tid < 128) {
        float s = 0.5f * (sV[tid] + sV[128 + tid]) + kb3[0];
        float sp = fmaxf(s, 0.f) + log1pf(expf(-fabsf(s)));
        int n_l = tid >> 4, m_l = tid & 15;
        R[(size_t)(b * NPTS + n0 + n_l) * NPTS + m0 + m_l] = sp;
    }
}

// ============ PointNet via per-wave MFMA: all 6 layers, 16 points per wave ============
// grid (16, 2), block 64. B-frags direct from pre-arranged global (1 dwordx4/lane).
__global__ __launch_bounds__(64) void k_pn_mfma(
    const float* __restrict__ emb, const _Float16* __restrict__ pnw,
    const float* __restrict__ pb0, const float* __restrict__ pb1,
    const float* __restrict__ pb2, const float* __restrict__ pb3,
    const float* __restrict__ pb4, const float* __restrict__ headw,
    float* __restrict__ wgt)
{
    const int n0 = blockIdx.x * 16, b = blockIdx.y;
    const int lane = threadIdx.x, l15 = lane & 15, quad = lane >> 4;
    __shared__ __align__(16) _Float16 sH[16][136];
    const float* xb = emb + b * FDIM * NPTS + n0 + l15;
    const _Float16* w0f = pnw;
    const _Float16* w1f = pnw + 32768;
    const _Float16* w2f = pnw + 36864;
    const _Float16* w3f = pnw + 40960;
    const _Float16* w4f = pnw + 49152;

    // ---- L0: 512 -> 64 ----
    floatx4 acc[4];
    #pragma unroll
    for (int nt = 0; nt < 4; ++nt) acc[nt] = (floatx4){0.f, 0.f, 0.f, 0.f};
    #pragma unroll 4
    for (int s = 0; s < 16; ++s) {
        const int cb = s * 32 + quad * 8;
        half8 af;
        #pragma unroll
        for (int e = 0; e < 8; ++e) af[e] = (_Float16)xb[(cb + e) * NPTS];
        #pragma unroll
        for (int nt = 0; nt < 4; ++nt) {
            half8 bf = *reinterpret_cast<const half8*>(w0f + ((s * 4 + nt) * 64 + lane) * 8);
            acc[nt] = __builtin_amdgcn_mfma_f32_16x16x32_f16(af, bf, acc[nt], 0, 0, 0);
        }
    }
    #pragma unroll
    for (int nt = 0; nt < 4; ++nt) {
        int o = nt * 16 + l15;
        float bv = pb0[o];
        #pragma unroll
        for (int r = 0; r < 4; ++r)
            sH[quad * 4 + r][o] = (_Float16)fmaxf(acc[nt][r] + bv, 0.f);
    }
    __syncthreads();

    // ---- L1, L2: 64 -> 64 ----
    const _Float16* wfs[2] = {w1f, w2f};
    const float* pbs[2] = {pb1, pb2};
    for (int layer = 0; layer < 2; ++layer) {
        half8 a0 = *reinterpret_cast<const half8*>(&sH[l15][quad * 8]);
        half8 a1 = *reinterpret_cast<const half8*>(&sH[l15][32 + quad * 8]);
        floatx4 ac[4];
        #pragma unroll
        for (int nt = 0; nt < 4; ++nt) {
            half8 b0 = *reinterpret_cast<const half8*>(wfs[layer] + (nt * 64 + lane) * 8);
            half8 b1 = *reinterpret_cast<const half8*>(wfs[layer] + ((4 + nt) * 64 + lane) * 8);
            ac[nt] = __builtin_amdgcn_mfma_f32_16x16x32_f16(a0, b0, (floatx4){0.f,0.f,0.f,0.f}, 0, 0, 0);
            ac[nt] = __builtin_amdgcn_mfma_f32_16x16x32_f16(a1, b1, ac[nt], 0, 0, 0);
        }
        __syncthreads();
        #pragma unroll
        for (int nt = 0; nt < 4; ++nt) {
            int o = nt * 16 + l15;
            float bv = pbs[layer][o];
            #pragma unroll
            for (int r = 0; r < 4; ++r)
                sH[quad * 4 + r][o] = (_Float16)fmaxf(ac[nt][r] + bv, 0.f);
        }
        __syncthreads();
    }

    // ---- L3: 64 -> 128 ----
    {
        half8 a0 = *reinterpret_cast<const half8*>(&sH[l15][quad * 8]);
        half8 a1 = *reinterpret_cast<const half8*>(&sH[l15][32 + quad * 8]);
        floatx4 ac[8];
        #pragma unroll
        for (int nt = 0; nt < 8; ++nt) {
            half8 b0 = *reinterpret_cast<const half8*>(w3f + (nt * 64 + lane) * 8);
            half8 b1 = *reinterpret_cast<const half8*>(w3f + ((8 + nt) * 64 + lane) * 8);
            ac[nt] = __builtin_amdgcn_mfma_f32_16x16x32_f16(a0, b0, (floatx4){0.f,0.f,0.f,0.f}, 0, 0, 0);
            ac[nt] = __builtin_amdgcn_mfma_f32_16x16x32_f16(a1, b1, ac[nt], 0, 0, 0);
        }
        __syncthreads();
        #pragma unroll
        for (int nt = 0; nt < 8; ++nt) {
            int o = nt * 16 + l15;
            float bv = pb3[o];
            #pragma unroll
            for (int r = 0; r < 4; ++r)
                sH[quad * 4 + r][o] = (_Float16)fmaxf(ac[nt][r] + bv, 0.f);
        }
        __syncthreads();
    }

    // ---- L4: 128 -> 512, fused with head dot ----
    half8 a4[4];
    #pragma unroll
    for (int s = 0; s < 4; ++s)
        a4[s] = *reinterpret_cast<const half8*>(&sH[l15][s * 32 + quad * 8]);
    float ps0 = 0.f, ps1 = 0.f, ps2 = 0.f, ps3 = 0.f;
    #pragma unroll 4
    for (int nt = 0; nt < 32; ++nt) {
        floatx4 a = (floatx4){0.f, 0.f, 0.f, 0.f};
        #pragma unroll
        for (int s = 0; s < 4; ++s) {
            half8 bf = *reinterpret_cast<const half8*>(w4f + ((s * 32 + nt) * 64 + lane) * 8);
            a = __builtin_amdgcn_mfma_f32_16x16x32_f16(a4[s], bf, a, 0, 0, 0);
        }
        int o = nt * 16 + l15;
        float hwv = headw[o], b4v = pb4[o];
        ps0 = fmaf(hwv, fmaxf(a[0] + b4v, 0.f), ps0);
        ps1 = fmaf(hwv, fmaxf(a[1] + b4v, 0.f), ps1);
        ps2 = fmaf(hwv, fmaxf(a[2] + b4v, 0.f), ps2);
        ps3 = fmaf(hwv, fmaxf(a[3] + b4v, 0.f), ps3);
    }
    #pragma unroll
    for (int m = 1; m < 16; m <<= 1) {
        ps0 += __shfl_xor(ps0, m, 64);
        ps1 += __shfl_xor(ps1, m, 64);
        ps2 += __shfl_xor(ps2, m, 64);
        ps3 += __shfl_xor(ps3, m, 64);
    }
    if (l15 == 0) {
        float* wb = wgt + b * NPTS + n0 + quad * 4;
        wb[0] = ps0; wb[1] = ps1; wb[2] = ps2; wb[3] = ps3;
    }
}

// ============ fused multilateration setup + solve + epilogue ============
__global__ __launch_bounds__(256) void k_solve(
    const float* __restrict__ R, const float* __restrict__ anchor_pts,
    const float* __restrict__ action_pts, const float* __restrict__ weight,
    float* __restrict__ out)
{
    const int a0 = blockIdx.x * 32, b = blockIdx.y;
    __shared__ float apx[256], apy[256], apz[256], sq[256];
    __shared__ float red[256];
    __shared__ float mb[12];
    const int t = threadIdx.x;
    const float px = anchor_pts[b * 768 + t];
    const float py = anchor_pts[b * 768 + 256 + t];
    const float pz = anchor_pts[b * 768 + 512 + t];
    apx[t] = px; apy[t] = py; apz[t] = pz;
    sq[t] = px * px + py * py + pz * pz;
    float sums[9];
    {
        float vals[9] = {px, py, pz, px*px, px*py, px*pz, py*py, py*pz, pz*pz};
        #pragma unroll
        for (int k = 0; k < 9; ++k) {
            red[t] = vals[k]; __syncthreads();
            for (int s = 128; s > 0; s >>= 1) {
                if (t < s) red[t] += red[t + s];
                __syncthreads();
            }
            sums[k] = red[0]; __syncthreads();
        }
    }
    if (t == 0) {
        const float inv = 1.f / 256.f;
        float mx = sums[0]*inv, my = sums[1]*inv, mz = sums[2]*inv;
        float a_ = sums[3]*inv - mx*mx;
        float b_ = sums[4]*inv - mx*my;
        float c_ = sums[5]*inv - mx*mz;
        float d_ = sums[6]*inv - my*my;
        float e_ = sums[7]*inv - my*mz;
        float f_ = sums[8]*inv - mz*mz;
        float c00 = d_*f_ - e_*e_;
        float c01 = c_*e_ - b_*f_;
        float c02 = b_*e_ - c_*d_;
        float det = a_*c00 + b_*c01 + c_*c02;
        float id = 1.f / det;
        mb[0] = mx; mb[1] = my; mb[2] = mz;
        mb[3] = c00*id;  mb[4] = c01*id;             mb[5] = c02*id;
        mb[6] = c01*id;  mb[7] = (a_*f_ - c_*c_)*id; mb[8] = (b_*c_ - a_*e_)*id;
        mb[9] = c02*id;  mb[10] = (b_*c_ - a_*e_)*id; mb[11] = (a_*d_ - b_*b_)*id;
    }
    __syncthreads();
    const int ar = a0 + (t >> 3), l8 = t & 7;
    const float Pbx = mb[0], Pby = mb[1], Pbz = mb[2];
    const float* Rrow = R + (size_t)(b * NPTS + ar) * NPTS;
    float v0 = 0.f, v1 = 0.f, v2 = 0.f;
    #pragma unroll 4
    for (int k = 0; k < 32; ++k) {
        int n = l8 + (k << 3);
        float Rv = Rrow[n];
        float cc = sq[n] - Rv * Rv;
        v0 = fmaf(cc, apx[n] - Pbx, v0);
        v1 = fmaf(cc, apy[n] - Pby, v1);
        v2 = fmaf(cc, apz[n] - Pbz, v2);
    }
    #pragma unroll
    for (int m = 1; m < 8; m <<= 1) {
        v0 += __shfl_xor(v0, m, 64);
        v1 += __shfl_xor(v1, m, 64);
        v2 += __shfl_xor(v2, m, 64);
    }
    if (l8 == 0) {
        const float sc = 0.5f / 256.f;
        v0 *= sc; v1 *= sc; v2 *= sc;
        float p0 = mb[3]*v0 + mb[4]*v1 + mb[5]*v2;
        float p1 = mb[6]*v0 + mb[7]*v1 + mb[8]*v2;
        float p2 = mb[9]*v0 + mb[10]*v1 + mb[11]*v2;
        float f0 = p0 - action_pts[b * 768 + ar];
        float f1 = p1 - action_pts[b * 768 + 256 + ar];
        float f2 = p2 - action_pts[b * 768 + 512 + ar];
        float wv = weight[b * NPTS + ar];
        out[b * 1024 + ar]              = f0;
        out[b * 1024 + 256 + ar]        = f1;
        out[b * 1024 + 512 + ar]        = f2;
        out[b * 1024 + 768 + ar]        = wv;
        out[2048 + b * 768 + ar]        = f0;
        out[2048 + b * 768 + 256 + ar]  = f1;
        out[2048 + b * 768 + 512 + ar]  = f2;
        out[3584 + b * 768 + ar]        = p0;
        out[3584 + b * 768 + 256 + ar]  = p1;
        out[3584 + b * 768 + 512 + ar]  = p2;
    }
}

extern "C" void kernel_launch(void* const* d_in, const int* in_sizes, int n_in,
                              void* d_out, int out_size, void* d_ws, size_t ws_size,
                              hipStream_t stream)
{
    const float* embA       = (const float*)d_in[0];
    const float* embB       = (const float*)d_in[1];
    const float* action_pts = (const float*)d_in[2];
    const float* anchor_pts = (const float*)d_in[3];
    const float* kw1 = (const float*)d_in[4];
    const float* kb1 = (const float*)d_in[5];
    const float* kw2 = (const float*)d_in[6];
    const float* kb2 = (const float*)d_in[7];
    const float* kw3 = (const float*)d_in[8];
    const float* kb3 = (const float*)d_in[9];
    const float* pw0 = (const float*)d_in[10];
    const float* pb0 = (const float*)d_in[11];
    const float* pw1 = (const float*)d_in[12];
    const float* pb1 = (const float*)d_in[13];
    const float* pw2 = (const float*)d_in[14];
    const float* pb2 = (const float*)d_in[15];
    const float* pw3 = (const float*)d_in[16];
    const float* pb3 = (const float*)d_in[17];
    const float* pw4 = (const float*)d_in[18];
    const float* pb4 = (const float*)d_in[19];
    const float* headw = (const float*)d_in[20];
    char* wsb = (char*)d_ws;
    float* out = (float*)d_out;

    _Float16* ap    = (_Float16*)(wsb + OFF_AP);
    _Float16* kw2f  = (_Float16*)(wsb + OFF_KW2F);
    _Float16* pnw   = (_Float16*)(wsb + OFF_PNW);
    _Float16* kw1f  = (_Float16*)(wsb + OFF_KW1F);
    float*    R     = (float*)(wsb + OFF_R);
    float*    wgt   = (float*)(wsb + OFF_WGT);

    hipLaunchKernelGGL(k_prep, dim3(1868), dim3(256), 0, stream,
                       kw2, kw1, pw0, pw1, pw2, pw3, pw4, kw2f, pnw, kw1f);
    hipLaunchKernelGGL(k_apart, dim3(16, 8), dim3(64), 0, stream,
                       embA, embB, kw1f, kb1, ap);
    hipLaunchKernelGGL(k_pn_mfma, dim3(16, 2), dim3(64), 0, stream,
                       embA, pnw, pb0, pb1, pb2, pb3, pb4, headw, wgt);
    hipLaunchKernelGGL(k_pair, dim3(16, 32, 2), dim3(256), 0, stream,
                       ap, kw2f, kb2, kw3, kb3, R);
    hipLaunchKernelGGL(k_solve, dim3(8, 2), dim3(256), 0, stream,
                       R, anchor_pts, action_pts, wgt, out);
}

// Round 4
// 166.949 us; speedup vs baseline: 2.5277x; 1.1887x over previous
//
#include <hip/hip_runtime.h>
#include <math.h>

#define NPTS 256
#define FDIM 512
#define H1   300
#define KP   320    // padded K (H1 -> 320)
#define H2   100
#define NP   112    // padded N (H2 -> 112)

typedef _Float16 half8  __attribute__((ext_vector_type(8)));
typedef _Float16 half2v __attribute__((ext_vector_type(2)));
typedef float    floatx4 __attribute__((ext_vector_type(4)));

// ---- workspace layout (byte offsets) ----
#define OFF_AP    0          // ap f16 [4 j][2 b][256 n][320 k]   : 1,310,720 B
#define OFF_KW2F  1310720    // kw2 f16 padded [112][320]         :    71,680 B
#define OFF_PNW   1382400    // pointnet weights f16 frag order   :   229,376 B
#define OFF_KW1F  1611776    // kw1 f16 frag order [2][16][20][512]: 655,360 B
#define OFF_R     2267136    // R fp32 [2][256][256]              :   524,288 B
#define OFF_WGT   2791424    // weight fp32 [2][256]              :     2,048 B

// ============ prep: cast/pad kw2; arrange pn + kw1 weights in B-frag order ============
__global__ __launch_bounds__(256) void k_prep(
    const float* __restrict__ kw2, const float* __restrict__ kw1,
    const float* __restrict__ pw0, const float* __restrict__ pw1,
    const float* __restrict__ pw2, const float* __restrict__ pw3,
    const float* __restrict__ pw4,
    _Float16* __restrict__ kw2f, _Float16* __restrict__ pnw,
    _Float16* __restrict__ kw1f)
{
    int idx = blockIdx.x * 256 + threadIdx.x;
    if (idx < 35840) {                       // kw2f [112][320]
        int g = idx / 320, h = idx - g * 320;
        kw2f[idx] = (_Float16)((g < H2 && h < H1) ? kw2[g * H1 + h] : 0.f);
        return;
    }
    int i = idx - 35840;
    if (i < 114688) {                        // pointnet frags
        const float* src; int K, NT, off;
        if      (i < 32768) { src = pw0; K = 512; NT = 4;  off = 0; }
        else if (i < 36864) { src = pw1; K = 64;  NT = 4;  off = 32768; }
        else if (i < 40960) { src = pw2; K = 64;  NT = 4;  off = 36864; }
        else if (i < 49152) { src = pw3; K = 64;  NT = 8;  off = 40960; }
        else                { src = pw4; K = 128; NT = 32; off = 49152; }
        int li = i - off;
        int e = li & 7, l = (li >> 3) & 63, r = li >> 9;
        int nt = r % NT, s = r / NT;
        int o = nt * 16 + (l & 15);
        int c = s * 32 + ((l >> 4) << 3) + e;
        pnw[i] = (_Float16)src[o * K + c];
        return;
    }
    i -= 114688;
    if (i < 327680) {                        // kw1 frags [half][s16][nt20][64][8]
        int e = i & 7, l = (i >> 3) & 63, r = i >> 9;     // r 0..639
        int nt = r % 20, s = (r / 20) & 15, half = r / 320;
        int h = nt * 16 + (l & 15);
        int c = s * 32 + ((l >> 4) << 3) + e;
        kw1f[i] = (_Float16)((h < H1) ? kw1[h * (2 * FDIM) + half * FDIM + c] : 0.f);
    }
}

// ============ Kernel A: first-layer GEMMs via MFMA, LDS-staged A, 4 waves/block ==========
// grid (16 ntiles, 8 jb), block 256. Block stages emb[512 f][16 n] -> LDS [n][f] f16,
// wave w computes h-tiles nt = 5w .. 5w+4 over full K.
#define XSTR 520   // f16 row stride for sX (2-way bank alias on b128 reads = free)
__global__ __launch_bounds__(256) void k_apart(
    const float* __restrict__ embA, const float* __restrict__ embB,
    const _Float16* __restrict__ kw1f, const float* __restrict__ kb1,
    _Float16* __restrict__ ap)
{
    const int ntile = blockIdx.x, jb = blockIdx.y;
    const int j = jb >> 1, b = jb & 1;
    const int n0 = ntile * 16;
    const int tid = threadIdx.x;
    const int wave = tid >> 6, lane = tid & 63;
    const int l15 = lane & 15, quad = lane >> 4;

    __shared__ __align__(16) _Float16 sX[16 * XSTR];

    const float* emb = ((j < 2) ? embA : embB) + b * FDIM * NPTS;
    // ---- stage: thread t handles n = t&15, f pair-base 2*(t>>4), step 32 ----
    {
        const int n = tid & 15, fp = tid >> 4;        // fp 0..15
        const float* src = emb + n0 + n;
        _Float16* dst = &sX[n * XSTR];
        #pragma unroll
        for (int i = 0; i < 16; ++i) {
            int f = 2 * fp + 32 * i;
            float e0 = src[(size_t)f * NPTS];
            float e1 = src[(size_t)(f + 1) * NPTS];
            half2v hv; hv.x = (_Float16)e0; hv.y = (_Float16)e1;
            *reinterpret_cast<half2v*>(&dst[f]) = hv;
        }
    }

    const _Float16* wf = kw1f + (size_t)(j & 1) * 163840;
    floatx4 acc[5];
    #pragma unroll
    for (int q = 0; q < 5; ++q) acc[q] = (floatx4){0.f, 0.f, 0.f, 0.f};

    __syncthreads();

    const _Float16* arow = &sX[l15 * XSTR + quad * 8];
    #pragma unroll 4
    for (int s = 0; s < 16; ++s) {
        half8 af = *reinterpret_cast<const half8*>(&arow[s * 32]);
        const _Float16* wrow = wf + ((size_t)(s * 20 + wave * 5) * 64 + lane) * 8;
        #pragma unroll
        for (int q = 0; q < 5; ++q) {
            half8 bf = *reinterpret_cast<const half8*>(wrow + q * 512);
            acc[q] = __builtin_amdgcn_mfma_f32_16x16x32_f16(af, bf, acc[q], 0, 0, 0);
        }
    }

    const bool addb = (j < 2);
    _Float16* apb = ap + (size_t)jb * NPTS * KP;
    #pragma unroll
    for (int q = 0; q < 5; ++q) {
        int nt = wave * 5 + q;
        int h = nt * 16 + l15;
        float bv = (addb && h < H1) ? kb1[h] : 0.f;
        #pragma unroll
        for (int r = 0; r < 4; ++r) {
            int n = n0 + quad * 4 + r;
            apb[(size_t)n * KP + h] = (_Float16)(acc[q][r] + bv);
        }
    }
}

// ============ Kernel B: fused pair tail via f16 MFMA ============
#define ASTR 328
#define PSTR 40
__global__ __launch_bounds__(256, 2) void k_pair(
    const _Float16* __restrict__ ap, const _Float16* __restrict__ kw2f,
    const float* __restrict__ kb2, const float* __restrict__ kw3,
    const float* __restrict__ kb3, float* __restrict__ R)
{
    const int mt = blockIdx.x, nt = blockIdx.y, b = blockIdx.z;
    const int m0 = mt * 16, n0 = nt * 8;
    __shared__ __align__(16) _Float16 sAB[48 * ASTR];
    __shared__ __align__(16) _Float16 sPre[256 * PSTR];
    __shared__ __align__(16) _Float16 sB[NP * PSTR];
    __shared__ float sV[256];
    const int tid = threadIdx.x;
    const int wave = tid >> 6, lane = tid & 63;
    const int l15 = lane & 15, quad = lane >> 4;

    for (int idx = tid; idx < 1920; idx += 256) {
        int row = idx / 40;
        int col = (idx - row * 40) * 8;
        int j, gn;
        if      (row < 8)  { j = 0; gn = n0 + row; }
        else if (row < 16) { j = 1; gn = n0 + row - 8; }
        else if (row < 32) { j = 2; gn = m0 + row - 16; }
        else               { j = 3; gn = m0 + row - 32; }
        half8 v = *reinterpret_cast<const half8*>(
            &ap[(size_t)((j * 2 + b) * NPTS + gn) * KP + col]);
        *reinterpret_cast<half8*>(&sAB[row * ASTR + col]) = v;
    }

    floatx4 acc[4][7];
    #pragma unroll
    for (int i = 0; i < 4; ++i)
        #pragma unroll
        for (int jj = 0; jj < 7; ++jj)
            acc[i][jj] = (floatx4){0.f, 0.f, 0.f, 0.f};

    const int sr = tid;
    const int s_tail = sr >> 7, s_n = (sr >> 4) & 7, s_m = sr & 15;
    const _Float16* arow = &sAB[(size_t)((s_tail ? 8 : 0) + s_n) * ASTR];
    const _Float16* brow = &sAB[(size_t)((s_tail ? 16 : 32) + s_m) * ASTR];
    const int rsw = sr + (sr >> 3);
    const int brw = (tid >> 1) + ((tid >> 1) >> 3);

    __syncthreads();

    for (int kc = 0; kc < 10; ++kc) {
        const int k0 = kc * 32;
        #pragma unroll
        for (int ko = 0; ko < 4; ++ko) {
            half8 av = *reinterpret_cast<const half8*>(&arow[k0 + ko * 8]);
            half8 bv = *reinterpret_cast<const half8*>(&brow[k0 + ko * 8]);
            half8 rv;
            #pragma unroll
            for (int e = 0; e < 8; ++e) {
                _Float16 x = av[e] + bv[e];
                rv[e] = x > (_Float16)0 ? x : (_Float16)0;
            }
            int ps = (ko + rsw) & 3;
            *reinterpret_cast<half8*>(&sPre[sr * PSTR + ps * 8]) = rv;
        }
        if (tid < 224) {
            int row = tid >> 1;
            #pragma unroll
            for (int q = 0; q < 2; ++q) {
                int sl = (tid & 1) * 2 + q;
                half8 v = *reinterpret_cast<const half8*>(
                    &kw2f[(size_t)row * KP + k0 + sl * 8]);
                int ps = (sl + brw) & 3;
                *reinterpret_cast<half8*>(&sB[row * PSTR + ps * 8]) = v;
            }
        }
        __syncthreads();
        half8 af[4];
        #pragma unroll
        for (int i = 0; i < 4; ++i) {
            int row = (wave * 4 + i) * 16 + l15;
            int ps = (quad + row + (row >> 3)) & 3;
            af[i] = *reinterpret_cast<const half8*>(&sPre[row * PSTR + ps * 8]);
        }
        #pragma unroll
        for (int jj = 0; jj < 7; ++jj) {
            int row = jj * 16 + l15;
            int ps = (quad + row + (row >> 3)) & 3;
            half8 bf = *reinterpret_cast<const half8*>(&sB[row * PSTR + ps * 8]);
            #pragma unroll
            for (int i = 0; i < 4; ++i)
                acc[i][jj] = __builtin_amdgcn_mfma_f32_16x16x32_f16(af[i], bf, acc[i][jj], 0, 0, 0);
        }
        __syncthreads();
    }

    float kw3v[7], kb2v[7];
    #pragma unroll
    for (int jj = 0; jj < 7; ++jj) {
        int g = jj * 16 + l15;
        kw3v[jj] = (g < H2) ? kw3[g] : 0.f;
        kb2v[jj] = (g < H2) ? kb2[g] : 0.f;
    }
    #pragma unroll
    for (int i = 0; i < 4; ++i) {
        float rv0 = 0.f, rv1 = 0.f, rv2 = 0.f, rv3 = 0.f;
        #pragma unroll
        for (int jj = 0; jj < 7; ++jj) {
            float w3 = kw3v[jj], b2 = kb2v[jj];
            rv0 = fmaf(w3, fmaxf(acc[i][jj][0] + b2, 0.f), rv0);
            rv1 = fmaf(w3, fmaxf(acc[i][jj][1] + b2, 0.f), rv1);
            rv2 = fmaf(w3, fmaxf(acc[i][jj][2] + b2, 0.f), rv2);
            rv3 = fmaf(w3, fmaxf(acc[i][jj][3] + b2, 0.f), rv3);
        }
        #pragma unroll
        for (int m = 1; m < 16; m <<= 1) {
            rv0 += __shfl_xor(rv0, m, 64);
            rv1 += __shfl_xor(rv1, m, 64);
            rv2 += __shfl_xor(rv2, m, 64);
            rv3 += __shfl_xor(rv3, m, 64);
        }
        if (l15 == 0) {
            int base = (wave * 4 + i) * 16 + quad * 4;
            sV[base + 0] = rv0; sV[base + 1] = rv1;
            sV[base + 2] = rv2; sV[base + 3] = rv3;
        }
    }
    __syncthreads();
    if (tid < 128) {
        float s = 0.5f * (sV[tid] + sV[128 + tid]) + kb3[0];
        float sp = fmaxf(s, 0.f) + log1pf(expf(-fabsf(s)));
        int n_l = tid >> 4, m_l = tid & 15;
        R[(size_t)(b * NPTS + n0 + n_l) * NPTS + m0 + m_l] = sp;
    }
}

// ============ PointNet via per-wave MFMA ============
__global__ __launch_bounds__(64) void k_pn_mfma(
    const float* __restrict__ emb, const _Float16* __restrict__ pnw,
    const float* __restrict__ pb0, const float* __restrict__ pb1,
    const float* __restrict__ pb2, const float* __restrict__ pb3,
    const float* __restrict__ pb4, const float* __restrict__ headw,
    float* __restrict__ wgt)
{
    const int n0 = blockIdx.x * 16, b = blockIdx.y;
    const int lane = threadIdx.x, l15 = lane & 15, quad = lane >> 4;
    __shared__ __align__(16) _Float16 sH[16][136];
    const float* xb = emb + b * FDIM * NPTS + n0 + l15;
    const _Float16* w0f = pnw;
    const _Float16* w1f = pnw + 32768;
    const _Float16* w2f = pnw + 36864;
    const _Float16* w3f = pnw + 40960;
    const _Float16* w4f = pnw + 49152;

    floatx4 acc[4];
    #pragma unroll
    for (int nt = 0; nt < 4; ++nt) acc[nt] = (floatx4){0.f, 0.f, 0.f, 0.f};
    #pragma unroll 4
    for (int s = 0; s < 16; ++s) {
        const int cb = s * 32 + quad * 8;
        half8 af;
        #pragma unroll
        for (int e = 0; e < 8; ++e) af[e] = (_Float16)xb[(cb + e) * NPTS];
        #pragma unroll
        for (int nt = 0; nt < 4; ++nt) {
            half8 bf = *reinterpret_cast<const half8*>(w0f + ((s * 4 + nt) * 64 + lane) * 8);
            acc[nt] = __builtin_amdgcn_mfma_f32_16x16x32_f16(af, bf, acc[nt], 0, 0, 0);
        }
    }
    #pragma unroll
    for (int nt = 0; nt < 4; ++nt) {
        int o = nt * 16 + l15;
        float bv = pb0[o];
        #pragma unroll
        for (int r = 0; r < 4; ++r)
            sH[quad * 4 + r][o] = (_Float16)fmaxf(acc[nt][r] + bv, 0.f);
    }
    __syncthreads();

    const _Float16* wfs[2] = {w1f, w2f};
    const float* pbs[2] = {pb1, pb2};
    for (int layer = 0; layer < 2; ++layer) {
        half8 a0 = *reinterpret_cast<const half8*>(&sH[l15][quad * 8]);
        half8 a1 = *reinterpret_cast<const half8*>(&sH[l15][32 + quad * 8]);
        floatx4 ac[4];
        #pragma unroll
        for (int nt = 0; nt < 4; ++nt) {
            half8 b0 = *reinterpret_cast<const half8*>(wfs[layer] + (nt * 64 + lane) * 8);
            half8 b1 = *reinterpret_cast<const half8*>(wfs[layer] + ((4 + nt) * 64 + lane) * 8);
            ac[nt] = __builtin_amdgcn_mfma_f32_16x16x32_f16(a0, b0, (floatx4){0.f,0.f,0.f,0.f}, 0, 0, 0);
            ac[nt] = __builtin_amdgcn_mfma_f32_16x16x32_f16(a1, b1, ac[nt], 0, 0, 0);
        }
        __syncthreads();
        #pragma unroll
        for (int nt = 0; nt < 4; ++nt) {
            int o = nt * 16 + l15;
            float bv = pbs[layer][o];
            #pragma unroll
            for (int r = 0; r < 4; ++r)
                sH[quad * 4 + r][o] = (_Float16)fmaxf(ac[nt][r] + bv, 0.f);
        }
        __syncthreads();
    }

    {
        half8 a0 = *reinterpret_cast<const half8*>(&sH[l15][quad * 8]);
        half8 a1 = *reinterpret_cast<const half8*>(&sH[l15][32 + quad * 8]);
        floatx4 ac[8];
        #pragma unroll
        for (int nt = 0; nt < 8; ++nt) {
            half8 b0 = *reinterpret_cast<const half8*>(w3f + (nt * 64 + lane) * 8);
            half8 b1 = *reinterpret_cast<const half8*>(w3f + ((8 + nt) * 64 + lane) * 8);
            ac[nt] = __builtin_amdgcn_mfma_f32_16x16x32_f16(a0, b0, (floatx4){0.f,0.f,0.f,0.f}, 0, 0, 0);
            ac[nt] = __builtin_amdgcn_mfma_f32_16x16x32_f16(a1, b1, ac[nt], 0, 0, 0);
        }
        __syncthreads();
        #pragma unroll
        for (int nt = 0; nt < 8; ++nt) {
            int o = nt * 16 + l15;
            float bv = pb3[o];
            #pragma unroll
            for (int r = 0; r < 4; ++r)
                sH[quad * 4 + r][o] = (_Float16)fmaxf(ac[nt][r] + bv, 0.f);
        }
        __syncthreads();
    }

    half8 a4[4];
    #pragma unroll
    for (int s = 0; s < 4; ++s)
        a4[s] = *reinterpret_cast<const half8*>(&sH[l15][s * 32 + quad * 8]);
    float ps0 = 0.f, ps1 = 0.f, ps2 = 0.f, ps3 = 0.f;
    #pragma unroll 4
    for (int nt = 0; nt < 32; ++nt) {
        floatx4 a = (floatx4){0.f, 0.f, 0.f, 0.f};
        #pragma unroll
        for (int s = 0; s < 4; ++s) {
            half8 bf = *reinterpret_cast<const half8*>(w4f + ((s * 32 + nt) * 64 + lane) * 8);
            a = __builtin_amdgcn_mfma_f32_16x16x32_f16(a4[s], bf, a, 0, 0, 0);
        }
        int o = nt * 16 + l15;
        float hwv = headw[o], b4v = pb4[o];
        ps0 = fmaf(hwv, fmaxf(a[0] + b4v, 0.f), ps0);
        ps1 = fmaf(hwv, fmaxf(a[1] + b4v, 0.f), ps1);
        ps2 = fmaf(hwv, fmaxf(a[2] + b4v, 0.f), ps2);
        ps3 = fmaf(hwv, fmaxf(a[3] + b4v, 0.f), ps3);
    }
    #pragma unroll
    for (int m = 1; m < 16; m <<= 1) {
        ps0 += __shfl_xor(ps0, m, 64);
        ps1 += __shfl_xor(ps1, m, 64);
        ps2 += __shfl_xor(ps2, m, 64);
        ps3 += __shfl_xor(ps3, m, 64);
    }
    if (l15 == 0) {
        float* wb = wgt + b * NPTS + n0 + quad * 4;
        wb[0] = ps0; wb[1] = ps1; wb[2] = ps2; wb[3] = ps3;
    }
}

// ============ fused multilateration setup + solve + epilogue ============
__global__ __launch_bounds__(256) void k_solve(
    const float* __restrict__ R, const float* __restrict__ anchor_pts,
    const float* __restrict__ action_pts, const float* __restrict__ weight,
    float* __restrict__ out)
{
    const int a0 = blockIdx.x * 32, b = blockIdx.y;
    __shared__ float apx[256], apy[256], apz[256], sq[256];
    __shared__ float red[256];
    __shared__ float mb[12];
    const int t = threadIdx.x;
    const float px = anchor_pts[b * 768 + t];
    const float py = anchor_pts[b * 768 + 256 + t];
    const float pz = anchor_pts[b * 768 + 512 + t];
    apx[t] = px; apy[t] = py; apz[t] = pz;
    sq[t] = px * px + py * py + pz * pz;
    float sums[9];
    {
        float vals[9] = {px, py, pz, px*px, px*py, px*pz, py*py, py*pz, pz*pz};
        #pragma unroll
        for (int k = 0; k < 9; ++k) {
            red[t] = vals[k]; __syncthreads();
            for (int s = 128; s > 0; s >>= 1) {
                if (t < s) red[t] += red[t + s];
                __syncthreads();
            }
            sums[k] = red[0]; __syncthreads();
        }
    }
    if (t == 0) {
        const float inv = 1.f / 256.f;
        float mx = sums[0]*inv, my = sums[1]*inv, mz = sums[2]*inv;
        float a_ = sums[3]*inv - mx*mx;
        float b_ = sums[4]*inv - mx*my;
        float c_ = sums[5]*inv - mx*mz;
        float d_ = sums[6]*inv - my*my;
        float e_ = sums[7]*inv - my*mz;
        float f_ = sums[8]*inv - mz*mz;
        float c00 = d_*f_ - e_*e_;
        float c01 = c_*e_ - b_*f_;
        float c02 = b_*e_ - c_*d_;
        float det = a_*c00 + b_*c01 + c_*c02;
        float id = 1.f / det;
        mb[0] = mx; mb[1] = my; mb[2] = mz;
        mb[3] = c00*id;  mb[4] = c01*id;             mb[5] = c02*id;
        mb[6] = c01*id;  mb[7] = (a_*f_ - c_*c_)*id; mb[8] = (b_*c_ - a_*e_)*id;
        mb[9] = c02*id;  mb[10] = (b_*c_ - a_*e_)*id; mb[11] = (a_*d_ - b_*b_)*id;
    }
    __syncthreads();
    const int ar = a0 + (t >> 3), l8 = t & 7;
    const float Pbx = mb[0], Pby = mb[1], Pbz = mb[2];
    const float* Rrow = R + (size_t)(b * NPTS + ar) * NPTS;
    float v0 = 0.f, v1 = 0.f, v2 = 0.f;
    #pragma unroll 4
    for (int k = 0; k < 32; ++k) {
        int n = l8 + (k << 3);
        float Rv = Rrow[n];
        float cc = sq[n] - Rv * Rv;
        v0 = fmaf(cc, apx[n] - Pbx, v0);
        v1 = fmaf(cc, apy[n] - Pby, v1);
        v2 = fmaf(cc, apz[n] - Pbz, v2);
    }
    #pragma unroll
    for (int m = 1; m < 8; m <<= 1) {
        v0 += __shfl_xor(v0, m, 64);
        v1 += __shfl_xor(v1, m, 64);
        v2 += __shfl_xor(v2, m, 64);
    }
    if (l8 == 0) {
        const float sc = 0.5f / 256.f;
        v0 *= sc; v1 *= sc; v2 *= sc;
        float p0 = mb[3]*v0 + mb[4]*v1 + mb[5]*v2;
        float p1 = mb[6]*v0 + mb[7]*v1 + mb[8]*v2;
        float p2 = mb[9]*v0 + mb[10]*v1 + mb[11]*v2;
        float f0 = p0 - action_pts[b * 768 + ar];
        float f1 = p1 - action_pts[b * 768 + 256 + ar];
        float f2 = p2 - action_pts[b * 768 + 512 + ar];
        float wv = weight[b * NPTS + ar];
        out[b * 1024 + ar]              = f0;
        out[b * 1024 + 256 + ar]        = f1;
        out[b * 1024 + 512 + ar]        = f2;
        out[b * 1024 + 768 + ar]        = wv;
        out[2048 + b * 768 + ar]        = f0;
        out[2048 + b * 768 + 256 + ar]  = f1;
        out[2048 + b * 768 + 512 + ar]  = f2;
        out[3584 + b * 768 + ar]        = p0;
        out[3584 + b * 768 + 256 + ar]  = p1;
        out[3584 + b * 768 + 512 + ar]  = p2;
    }
}

extern "C" void kernel_launch(void* const* d_in, const int* in_sizes, int n_in,
                              void* d_out, int out_size, void* d_ws, size_t ws_size,
                              hipStream_t stream)
{
    const float* embA       = (const float*)d_in[0];
    const float* embB       = (const float*)d_in[1];
    const float* action_pts = (const float*)d_in[2];
    const float* anchor_pts = (const float*)d_in[3];
    const float* kw1 = (const float*)d_in[4];
    const float* kb1 = (const float*)d_in[5];
    const float* kw2 = (const float*)d_in[6];
    const float* kb2 = (const float*)d_in[7];
    const float* kw3 = (const float*)d_in[8];
    const float* kb3 = (const float*)d_in[9];
    const float* pw0 = (const float*)d_in[10];
    const float* pb0 = (const float*)d_in[11];
    const float* pw1 = (const float*)d_in[12];
    const float* pb1 = (const float*)d_in[13];
    const float* pw2 = (const float*)d_in[14];
    const float* pb2 = (const float*)d_in[15];
    const float* pw3 = (const float*)d_in[16];
    const float* pb3 = (const float*)d_in[17];
    const float* pw4 = (const float*)d_in[18];
    const float* pb4 = (const float*)d_in[19];
    const float* headw = (const float*)d_in[20];
    char* wsb = (char*)d_ws;
    float* out = (float*)d_out;

    _Float16* ap    = (_Float16*)(wsb + OFF_AP);
    _Float16* kw2f  = (_Float16*)(wsb + OFF_KW2F);
    _Float16* pnw   = (_Float16*)(wsb + OFF_PNW);
    _Float16* kw1f  = (_Float16*)(wsb + OFF_KW1F);
    float*    R     = (float*)(wsb + OFF_R);
    float*    wgt   = (float*)(wsb + OFF_WGT);

    hipLaunchKernelGGL(k_prep, dim3(1868), dim3(256), 0, stream,
                       kw2, kw1, pw0, pw1, pw2, pw3, pw4, kw2f, pnw, kw1f);
    hipLaunchKernelGGL(k_apart, dim3(16, 8), dim3(256), 0, stream,
                       embA, embB, kw1f, kb1, ap);
    hipLaunchKernelGGL(k_pn_mfma, dim3(16, 2), dim3(64), 0, stream,
                       embA, pnw, pb0, pb1, pb2, pb3, pb4, headw, wgt);
    hipLaunchKernelGGL(k_pair, dim3(16, 32, 2), dim3(256), 0, stream,
                       ap, kw2f, kb2, kw3, kb3, R);
    hipLaunchKernelGGL(k_solve, dim3(8, 2), dim3(256), 0, stream,
                       R, anchor_pts, action_pts, wgt, out);
}

// Round 5
// 159.325 us; speedup vs baseline: 2.6487x; 1.0479x over previous
//
#include <hip/hip_runtime.h>
#include <math.h>

#define NPTS 256
#define FDIM 512
#define H1   300
#define KP   320    // padded K (H1 -> 320)
#define H2   100
#define NP   112    // padded N (H2 -> 112)

typedef _Float16 half8  __attribute__((ext_vector_type(8)));
typedef _Float16 half2v __attribute__((ext_vector_type(2)));
typedef float    floatx4 __attribute__((ext_vector_type(4)));

// ---- workspace layout (byte offsets) ----
#define OFF_AP    0          // ap f16 [4 j][2 b][256 n][320 k]   : 1,310,720 B
#define OFF_KW2F  1310720    // kw2 f16 B-frag order [10][7][64][8]: 71,680 B
#define OFF_PNW   1382400    // pointnet weights f16 frag order   :   229,376 B
#define OFF_KW1F  1611776    // kw1 f16 frag order [2][16][20][512]: 655,360 B
#define OFF_R     2267136    // R fp32 [2][256][256]              :   524,288 B
#define OFF_WGT   2791424    // weight fp32 [2][256]              :     2,048 B

// ============ prep: kw2 -> B-frag order; pn + kw1 weights -> B-frag order ============
// B-frag (mfma_f32_16x16x32_f16): lane l holds B[k][n] with n = nt*16 + (l&15),
// k = s*32 + (l>>4)*8 + e, e=0..7 contiguous -> one dwordx4 per lane at runtime.
__global__ __launch_bounds__(256) void k_prep(
    const float* __restrict__ kw2, const float* __restrict__ kw1,
    const float* __restrict__ pw0, const float* __restrict__ pw1,
    const float* __restrict__ pw2, const float* __restrict__ pw3,
    const float* __restrict__ pw4,
    _Float16* __restrict__ kw2ff, _Float16* __restrict__ pnw,
    _Float16* __restrict__ kw1f)
{
    int idx = blockIdx.x * 256 + threadIdx.x;
    if (idx < 35840) {                       // kw2ff [kc10][nt7][64][8]
        int e = idx & 7, lane = (idx >> 3) & 63, r = idx >> 9;   // r 0..69
        int nt = r % 7, kc = r / 7;
        int g = nt * 16 + (lane & 15);
        int k = kc * 32 + ((lane >> 4) << 3) + e;
        kw2ff[idx] = (_Float16)((g < H2 && k < H1) ? kw2[g * H1 + k] : 0.f);
        return;
    }
    int i = idx - 35840;
    if (i < 114688) {                        // pointnet frags
        const float* src; int K, NT, off;
        if      (i < 32768) { src = pw0; K = 512; NT = 4;  off = 0; }
        else if (i < 36864) { src = pw1; K = 64;  NT = 4;  off = 32768; }
        else if (i < 40960) { src = pw2; K = 64;  NT = 4;  off = 36864; }
        else if (i < 49152) { src = pw3; K = 64;  NT = 8;  off = 40960; }
        else                { src = pw4; K = 128; NT = 32; off = 49152; }
        int li = i - off;
        int e = li & 7, l = (li >> 3) & 63, r = li >> 9;
        int nt = r % NT, s = r / NT;
        int o = nt * 16 + (l & 15);
        int c = s * 32 + ((l >> 4) << 3) + e;
        pnw[i] = (_Float16)src[o * K + c];
        return;
    }
    i -= 114688;
    if (i < 327680) {                        // kw1 frags [half][s16][nt20][64][8]
        int e = i & 7, l = (i >> 3) & 63, r = i >> 9;     // r 0..639
        int nt = r % 20, s = (r / 20) & 15, half = r / 320;
        int h = nt * 16 + (l & 15);
        int c = s * 32 + ((l >> 4) << 3) + e;
        kw1f[i] = (_Float16)((h < H1) ? kw1[h * (2 * FDIM) + half * FDIM + c] : 0.f);
    }
}

// ============ Kernel A: first-layer GEMMs via MFMA, LDS-staged A, 4 waves/block ==========
#define XSTR 520
__global__ __launch_bounds__(256) void k_apart(
    const float* __restrict__ embA, const float* __restrict__ embB,
    const _Float16* __restrict__ kw1f, const float* __restrict__ kb1,
    _Float16* __restrict__ ap)
{
    const int ntile = blockIdx.x, jb = blockIdx.y;
    const int j = jb >> 1, b = jb & 1;
    const int n0 = ntile * 16;
    const int tid = threadIdx.x;
    const int wave = tid >> 6, lane = tid & 63;
    const int l15 = lane & 15, quad = lane >> 4;

    __shared__ __align__(16) _Float16 sX[16 * XSTR];

    const float* emb = ((j < 2) ? embA : embB) + b * FDIM * NPTS;
    {
        const int n = tid & 15, fp = tid >> 4;
        const float* src = emb + n0 + n;
        _Float16* dst = &sX[n * XSTR];
        #pragma unroll
        for (int i = 0; i < 16; ++i) {
            int f = 2 * fp + 32 * i;
            float e0 = src[(size_t)f * NPTS];
            float e1 = src[(size_t)(f + 1) * NPTS];
            half2v hv; hv.x = (_Float16)e0; hv.y = (_Float16)e1;
            *reinterpret_cast<half2v*>(&dst[f]) = hv;
        }
    }

    const _Float16* wf = kw1f + (size_t)(j & 1) * 163840;
    floatx4 acc[5];
    #pragma unroll
    for (int q = 0; q < 5; ++q) acc[q] = (floatx4){0.f, 0.f, 0.f, 0.f};

    __syncthreads();

    const _Float16* arow = &sX[l15 * XSTR + quad * 8];
    #pragma unroll 4
    for (int s = 0; s < 16; ++s) {
        half8 af = *reinterpret_cast<const half8*>(&arow[s * 32]);
        const _Float16* wrow = wf + ((size_t)(s * 20 + wave * 5) * 64 + lane) * 8;
        #pragma unroll
        for (int q = 0; q < 5; ++q) {
            half8 bf = *reinterpret_cast<const half8*>(wrow + q * 512);
            acc[q] = __builtin_amdgcn_mfma_f32_16x16x32_f16(af, bf, acc[q], 0, 0, 0);
        }
    }

    const bool addb = (j < 2);
    _Float16* apb = ap + (size_t)jb * NPTS * KP;
    #pragma unroll
    for (int q = 0; q < 5; ++q) {
        int nt = wave * 5 + q;
        int h = nt * 16 + l15;
        float bv = (addb && h < H1) ? kb1[h] : 0.f;
        #pragma unroll
        for (int r = 0; r < 4; ++r) {
            int n = n0 + quad * 4 + r;
            apb[(size_t)n * KP + h] = (_Float16)(acc[q][r] + bv);
        }
    }
}

// ============ Kernel B: fused pair tail via f16 MFMA — register A-frags, no K-loop barriers ====
// M=256 rows = tail*128 + n*16 + m ; wave w owns M-tiles 4w..4w+3 (tail=w>>1, n=(w&1)*4+i).
// Within a tile all rows share a-row n -> A-frag = relu(b_frag + a_broadcast) in registers.
#define SA_STR 328
__global__ __launch_bounds__(256, 2) void k_pair(
    const _Float16* __restrict__ ap, const _Float16* __restrict__ kw2ff,
    const float* __restrict__ kb2, const float* __restrict__ kw3,
    const float* __restrict__ kb3, float* __restrict__ R)
{
    const int mt = blockIdx.x, nt = blockIdx.y, b = blockIdx.z;
    const int m0 = mt * 16, n0 = nt * 8;
    __shared__ __align__(16) _Float16 sA[16 * SA_STR];       // a1/a2 rows, 10.5 KB
    __shared__ __align__(16) _Float16 sBT[2 * 10 * 64 * 8];  // b-frags, 20 KB
    __shared__ float sV[256];
    const int tid = threadIdx.x;
    const int wave = tid >> 6, lane = tid & 63;
    const int l15 = lane & 15, quad = lane >> 4;

    // ---- stage a-rows [t2][8 n][320] : t0=a1, t1=a2 ----
    for (int idx = tid; idx < 640; idx += 256) {
        int row = idx / 40, col = (idx - row * 40) * 8;
        int t = row >> 3, r = row & 7;
        half8 v = *reinterpret_cast<const half8*>(
            &ap[(size_t)((t * 2 + b) * NPTS + n0 + r) * KP + col]);
        *reinterpret_cast<half8*>(&sA[row * SA_STR + col]) = v;
    }
    // ---- stage b-rows in frag order: sBT[t][kc][lane][8] ; t0<-b2(j3), t1<-b1(j2) ----
    for (int idx = tid; idx < 1280; idx += 256) {
        int ln = idx & 63, kc = (idx >> 6) % 10, t = idx / 640;
        int j = t ? 2 : 3;
        half8 v = *reinterpret_cast<const half8*>(
            &ap[(size_t)((j * 2 + b) * NPTS + m0 + (ln & 15)) * KP + kc * 32 + ((ln >> 4) << 3)]);
        *reinterpret_cast<half8*>(&sBT[(size_t)idx * 8]) = v;
    }
    __syncthreads();   // only barrier before epilogue

    const int tail = wave >> 1;
    const _Float16* sBTt = &sBT[(size_t)tail * 10 * 64 * 8 + (size_t)lane * 8];
    const _Float16* aRow0 = &sA[(size_t)(tail * 8 + (wave & 1) * 4) * SA_STR + quad * 8];
    const _Float16* kwf = kw2ff + (size_t)lane * 8;

    floatx4 acc[4][7];
    #pragma unroll
    for (int i = 0; i < 4; ++i)
        #pragma unroll
        for (int jj = 0; jj < 7; ++jj)
            acc[i][jj] = (floatx4){0.f, 0.f, 0.f, 0.f};

    for (int kc = 0; kc < 10; ++kc) {
        half8 bfrag = *reinterpret_cast<const half8*>(&sBTt[(size_t)kc * 64 * 8]);
        half8 af[4];
        #pragma unroll
        for (int i = 0; i < 4; ++i) {
            half8 av = *reinterpret_cast<const half8*>(&aRow0[i * SA_STR + kc * 32]);
            half8 s = av + bfrag;
            half8 rv;
            #pragma unroll
            for (int e = 0; e < 8; ++e)
                rv[e] = s[e] > (_Float16)0 ? s[e] : (_Float16)0;
            af[i] = rv;
        }
        #pragma unroll
        for (int jj = 0; jj < 7; ++jj) {
            half8 bw = *reinterpret_cast<const half8*>(&kwf[(size_t)(kc * 7 + jj) * 64 * 8]);
            #pragma unroll
            for (int i = 0; i < 4; ++i)
                acc[i][jj] = __builtin_amdgcn_mfma_f32_16x16x32_f16(af[i], bw, acc[i][jj], 0, 0, 0);
        }
    }

    // ---- epilogue: bias+relu layer2, dot kw3, reduce over g(l15), combine tails ----
    float kw3v[7], kb2v[7];
    #pragma unroll
    for (int jj = 0; jj < 7; ++jj) {
        int g = jj * 16 + l15;
        kw3v[jj] = (g < H2) ? kw3[g] : 0.f;
        kb2v[jj] = (g < H2) ? kb2[g] : 0.f;
    }
    #pragma unroll
    for (int i = 0; i < 4; ++i) {
        float rv0 = 0.f, rv1 = 0.f, rv2 = 0.f, rv3 = 0.f;
        #pragma unroll
        for (int jj = 0; jj < 7; ++jj) {
            float w3 = kw3v[jj], b2 = kb2v[jj];
            rv0 = fmaf(w3, fmaxf(acc[i][jj][0] + b2, 0.f), rv0);
            rv1 = fmaf(w3, fmaxf(acc[i][jj][1] + b2, 0.f), rv1);
            rv2 = fmaf(w3, fmaxf(acc[i][jj][2] + b2, 0.f), rv2);
            rv3 = fmaf(w3, fmaxf(acc[i][jj][3] + b2, 0.f), rv3);
        }
        #pragma unroll
        for (int m = 1; m < 16; m <<= 1) {
            rv0 += __shfl_xor(rv0, m, 64);
            rv1 += __shfl_xor(rv1, m, 64);
            rv2 += __shfl_xor(rv2, m, 64);
            rv3 += __shfl_xor(rv3, m, 64);
        }
        if (l15 == 0) {
            int base = (wave * 4 + i) * 16 + quad * 4;
            sV[base + 0] = rv0; sV[base + 1] = rv1;
            sV[base + 2] = rv2; sV[base + 3] = rv3;
        }
    }
    __syncthreads();
    if (tid < 128) {
        float s = 0.5f * (sV[tid] + sV[128 + tid]) + kb3[0];
        float sp = fmaxf(s, 0.f) + log1pf(expf(-fabsf(s)));
        int n_l = tid >> 4, m_l = tid & 15;
        R[(size_t)(b * NPTS + n0 + n_l) * NPTS + m0 + m_l] = sp;
    }
}

// ============ PointNet via per-wave MFMA ============
__global__ __launch_bounds__(64) void k_pn_mfma(
    const float* __restrict__ emb, const _Float16* __restrict__ pnw,
    const float* __restrict__ pb0, const float* __restrict__ pb1,
    const float* __restrict__ pb2, const float* __restrict__ pb3,
    const float* __restrict__ pb4, const float* __restrict__ headw,
    float* __restrict__ wgt)
{
    const int n0 = blockIdx.x * 16, b = blockIdx.y;
    const int lane = threadIdx.x, l15 = lane & 15, quad = lane >> 4;
    __shared__ __align__(16) _Float16 sH[16][136];
    const float* xb = emb + b * FDIM * NPTS + n0 + l15;
    const _Float16* w0f = pnw;
    const _Float16* w1f = pnw + 32768;
    const _Float16* w2f = pnw + 36864;
    const _Float16* w3f = pnw + 40960;
    const _Float16* w4f = pnw + 49152;

    floatx4 acc[4];
    #pragma unroll
    for (int nt = 0; nt < 4; ++nt) acc[nt] = (floatx4){0.f, 0.f, 0.f, 0.f};
    #pragma unroll 4
    for (int s = 0; s < 16; ++s) {
        const int cb = s * 32 + quad * 8;
        half8 af;
        #pragma unroll
        for (int e = 0; e < 8; ++e) af[e] = (_Float16)xb[(cb + e) * NPTS];
        #pragma unroll
        for (int nt = 0; nt < 4; ++nt) {
            half8 bf = *reinterpret_cast<const half8*>(w0f + ((s * 4 + nt) * 64 + lane) * 8);
            acc[nt] = __builtin_amdgcn_mfma_f32_16x16x32_f16(af, bf, acc[nt], 0, 0, 0);
        }
    }
    #pragma unroll
    for (int nt = 0; nt < 4; ++nt) {
        int o = nt * 16 + l15;
        float bv = pb0[o];
        #pragma unroll
        for (int r = 0; r < 4; ++r)
            sH[quad * 4 + r][o] = (_Float16)fmaxf(acc[nt][r] + bv, 0.f);
    }
    __syncthreads();

    const _Float16* wfs[2] = {w1f, w2f};
    const float* pbs[2] = {pb1, pb2};
    for (int layer = 0; layer < 2; ++layer) {
        half8 a0 = *reinterpret_cast<const half8*>(&sH[l15][quad * 8]);
        half8 a1 = *reinterpret_cast<const half8*>(&sH[l15][32 + quad * 8]);
        floatx4 ac[4];
        #pragma unroll
        for (int nt = 0; nt < 4; ++nt) {
            half8 b0 = *reinterpret_cast<const half8*>(wfs[layer] + (nt * 64 + lane) * 8);
            half8 b1 = *reinterpret_cast<const half8*>(wfs[layer] + ((4 + nt) * 64 + lane) * 8);
            ac[nt] = __builtin_amdgcn_mfma_f32_16x16x32_f16(a0, b0, (floatx4){0.f,0.f,0.f,0.f}, 0, 0, 0);
            ac[nt] = __builtin_amdgcn_mfma_f32_16x16x32_f16(a1, b1, ac[nt], 0, 0, 0);
        }
        __syncthreads();
        #pragma unroll
        for (int nt = 0; nt < 4; ++nt) {
            int o = nt * 16 + l15;
            float bv = pbs[layer][o];
            #pragma unroll
            for (int r = 0; r < 4; ++r)
                sH[quad * 4 + r][o] = (_Float16)fmaxf(ac[nt][r] + bv, 0.f);
        }
        __syncthreads();
    }

    {
        half8 a0 = *reinterpret_cast<const half8*>(&sH[l15][quad * 8]);
        half8 a1 = *reinterpret_cast<const half8*>(&sH[l15][32 + quad * 8]);
        floatx4 ac[8];
        #pragma unroll
        for (int nt = 0; nt < 8; ++nt) {
            half8 b0 = *reinterpret_cast<const half8*>(w3f + (nt * 64 + lane) * 8);
            half8 b1 = *reinterpret_cast<const half8*>(w3f + ((8 + nt) * 64 + lane) * 8);
            ac[nt] = __builtin_amdgcn_mfma_f32_16x16x32_f16(a0, b0, (floatx4){0.f,0.f,0.f,0.f}, 0, 0, 0);
            ac[nt] = __builtin_amdgcn_mfma_f32_16x16x32_f16(a1, b1, ac[nt], 0, 0, 0);
        }
        __syncthreads();
        #pragma unroll
        for (int nt = 0; nt < 8; ++nt) {
            int o = nt * 16 + l15;
            float bv = pb3[o];
            #pragma unroll
            for (int r = 0; r < 4; ++r)
                sH[quad * 4 + r][o] = (_Float16)fmaxf(ac[nt][r] + bv, 0.f);
        }
        __syncthreads();
    }

    half8 a4[4];
    #pragma unroll
    for (int s = 0; s < 4; ++s)
        a4[s] = *reinterpret_cast<const half8*>(&sH[l15][s * 32 + quad * 8]);
    float ps0 = 0.f, ps1 = 0.f, ps2 = 0.f, ps3 = 0.f;
    #pragma unroll 4
    for (int nt = 0; nt < 32; ++nt) {
        floatx4 a = (floatx4){0.f, 0.f, 0.f, 0.f};
        #pragma unroll
        for (int s = 0; s < 4; ++s) {
            half8 bf = *reinterpret_cast<const half8*>(w4f + ((s * 32 + nt) * 64 + lane) * 8);
            a = __builtin_amdgcn_mfma_f32_16x16x32_f16(a4[s], bf, a, 0, 0, 0);
        }
        int o = nt * 16 + l15;
        float hwv = headw[o], b4v = pb4[o];
        ps0 = fmaf(hwv, fmaxf(a[0] + b4v, 0.f), ps0);
        ps1 = fmaf(hwv, fmaxf(a[1] + b4v, 0.f), ps1);
        ps2 = fmaf(hwv, fmaxf(a[2] + b4v, 0.f), ps2);
        ps3 = fmaf(hwv, fmaxf(a[3] + b4v, 0.f), ps3);
    }
    #pragma unroll
    for (int m = 1; m < 16; m <<= 1) {
        ps0 += __shfl_xor(ps0, m, 64);
        ps1 += __shfl_xor(ps1, m, 64);
        ps2 += __shfl_xor(ps2, m, 64);
        ps3 += __shfl_xor(ps3, m, 64);
    }
    if (l15 == 0) {
        float* wb = wgt + b * NPTS + n0 + quad * 4;
        wb[0] = ps0; wb[1] = ps1; wb[2] = ps2; wb[3] = ps3;
    }
}

// ============ fused multilateration setup + solve + epilogue ============
__global__ __launch_bounds__(256) void k_solve(
    const float* __restrict__ R, const float* __restrict__ anchor_pts,
    const float* __restrict__ action_pts, const float* __restrict__ weight,
    float* __restrict__ out)
{
    const int a0 = blockIdx.x * 32, b = blockIdx.y;
    __shared__ float apx[256], apy[256], apz[256], sq[256];
    __shared__ float red[256];
    __shared__ float mb[12];
    const int t = threadIdx.x;
    const float px = anchor_pts[b * 768 + t];
    const float py = anchor_pts[b * 768 + 256 + t];
    const float pz = anchor_pts[b * 768 + 512 + t];
    apx[t] = px; apy[t] = py; apz[t] = pz;
    sq[t] = px * px + py * py + pz * pz;
    float sums[9];
    {
        float vals[9] = {px, py, pz, px*px, px*py, px*pz, py*py, py*pz, pz*pz};
        #pragma unroll
        for (int k = 0; k < 9; ++k) {
            red[t] = vals[k]; __syncthreads();
            for (int s = 128; s > 0; s >>= 1) {
                if (t < s) red[t] += red[t + s];
                __syncthreads();
            }
            sums[k] = red[0]; __syncthreads();
        }
    }
    if (t == 0) {
        const float inv = 1.f / 256.f;
        float mx = sums[0]*inv, my = sums[1]*inv, mz = sums[2]*inv;
        float a_ = sums[3]*inv - mx*mx;
        float b_ = sums[4]*inv - mx*my;
        float c_ = sums[5]*inv - mx*mz;
        float d_ = sums[6]*inv - my*my;
        float e_ = sums[7]*inv - my*mz;
        float f_ = sums[8]*inv - mz*mz;
        float c00 = d_*f_ - e_*e_;
        float c01 = c_*e_ - b_*f_;
        float c02 = b_*e_ - c_*d_;
        float det = a_*c00 + b_*c01 + c_*c02;
        float id = 1.f / det;
        mb[0] = mx; mb[1] = my; mb[2] = mz;
        mb[3] = c00*id;  mb[4] = c01*id;             mb[5] = c02*id;
        mb[6] = c01*id;  mb[7] = (a_*f_ - c_*c_)*id; mb[8] = (b_*c_ - a_*e_)*id;
        mb[9] = c02*id;  mb[10] = (b_*c_ - a_*e_)*id; mb[11] = (a_*d_ - b_*b_)*id;
    }
    __syncthreads();
    const int ar = a0 + (t >> 3), l8 = t & 7;
    const float Pbx = mb[0], Pby = mb[1], Pbz = mb[2];
    const float* Rrow = R + (size_t)(b * NPTS + ar) * NPTS;
    float v0 = 0.f, v1 = 0.f, v2 = 0.f;
    #pragma unroll 4
    for (int k = 0; k < 32; ++k) {
        int n = l8 + (k << 3);
        float Rv = Rrow[n];
        float cc = sq[n] - Rv * Rv;
        v0 = fmaf(cc, apx[n] - Pbx, v0);
        v1 = fmaf(cc, apy[n] - Pby, v1);
        v2 = fmaf(cc, apz[n] - Pbz, v2);
    }
    #pragma unroll
    for (int m = 1; m < 8; m <<= 1) {
        v0 += __shfl_xor(v0, m, 64);
        v1 += __shfl_xor(v1, m, 64);
        v2 += __shfl_xor(v2, m, 64);
    }
    if (l8 == 0) {
        const float sc = 0.5f / 256.f;
        v0 *= sc; v1 *= sc; v2 *= sc;
        float p0 = mb[3]*v0 + mb[4]*v1 + mb[5]*v2;
        float p1 = mb[6]*v0 + mb[7]*v1 + mb[8]*v2;
        float p2 = mb[9]*v0 + mb[10]*v1 + mb[11]*v2;
        float f0 = p0 - action_pts[b * 768 + ar];
        float f1 = p1 - action_pts[b * 768 + 256 + ar];
        float f2 = p2 - action_pts[b * 768 + 512 + ar];
        float wv = weight[b * NPTS + ar];
        out[b * 1024 + ar]              = f0;
        out[b * 1024 + 256 + ar]        = f1;
        out[b * 1024 + 512 + ar]        = f2;
        out[b * 1024 + 768 + ar]        = wv;
        out[2048 + b * 768 + ar]        = f0;
        out[2048 + b * 768 + 256 + ar]  = f1;
        out[2048 + b * 768 + 512 + ar]  = f2;
        out[3584 + b * 768 + ar]        = p0;
        out[3584 + b * 768 + 256 + ar]  = p1;
        out[3584 + b * 768 + 512 + ar]  = p2;
    }
}

extern "C" void kernel_launch(void* const* d_in, const int* in_sizes, int n_in,
                              void* d_out, int out_size, void* d_ws, size_t ws_size,
                              hipStream_t stream)
{
    const float* embA       = (const float*)d_in[0];
    const float* embB       = (const float*)d_in[1];
    const float* action_pts = (const float*)d_in[2];
    const float* anchor_pts = (const float*)d_in[3];
    const float* kw1 = (const float*)d_in[4];
    const float* kb1 = (const float*)d_in[5];
    const float* kw2 = (const float*)d_in[6];
    const float* kb2 = (const float*)d_in[7];
    const float* kw3 = (const float*)d_in[8];
    const float* kb3 = (const float*)d_in[9];
    const float* pw0 = (const float*)d_in[10];
    const float* pb0 = (const float*)d_in[11];
    const float* pw1 = (const float*)d_in[12];
    const float* pb1 = (const float*)d_in[13];
    const float* pw2 = (const float*)d_in[14];
    const float* pb2 = (const float*)d_in[15];
    const float* pw3 = (const float*)d_in[16];
    const float* pb3 = (const float*)d_in[17];
    const float* pw4 = (const float*)d_in[18];
    const float* pb4 = (const float*)d_in[19];
    const float* headw = (const float*)d_in[20];
    char* wsb = (char*)d_ws;
    float* out = (float*)d_out;

    _Float16* ap    = (_Float16*)(wsb + OFF_AP);
    _Float16* kw2ff = (_Float16*)(wsb + OFF_KW2F);
    _Float16* pnw   = (_Float16*)(wsb + OFF_PNW);
    _Float16* kw1f  = (_Float16*)(wsb + OFF_KW1F);
    float*    R     = (float*)(wsb + OFF_R);
    float*    wgt   = (float*)(wsb + OFF_WGT);

    hipLaunchKernelGGL(k_prep, dim3(1868), dim3(256), 0, stream,
                       kw2, kw1, pw0, pw1, pw2, pw3, pw4, kw2ff, pnw, kw1f);
    hipLaunchKernelGGL(k_apart, dim3(16, 8), dim3(256), 0, stream,
                       embA, embB, kw1f, kb1, ap);
    hipLaunchKernelGGL(k_pn_mfma, dim3(16, 2), dim3(64), 0, stream,
                       embA, pnw, pb0, pb1, pb2, pb3, pb4, headw, wgt);
    hipLaunchKernelGGL(k_pair, dim3(16, 32, 2), dim3(256), 0, stream,
                       ap, kw2ff, kb2, kw3, kb3, R);
    hipLaunchKernelGGL(k_solve, dim3(8, 2), dim3(256), 0, stream,
                       R, anchor_pts, action_pts, wgt, out);
}

// Round 6
// 151.266 us; speedup vs baseline: 2.7898x; 1.0533x over previous
//
#include <hip/hip_runtime.h>
#include <math.h>

#define NPTS 256
#define FDIM 512
#define H1   300
#define KP   320    // padded K (H1 -> 320)
#define H2   100
#define NP   112    // padded N (H2 -> 112)

typedef _Float16 half8  __attribute__((ext_vector_type(8)));
typedef _Float16 half2v __attribute__((ext_vector_type(2)));
typedef float    floatx4 __attribute__((ext_vector_type(4)));

// ---- workspace layout (byte offsets) ----
#define OFF_AP    0          // ap f16 [4 j][2 b][256 n][320 k]   : 1,310,720 B
#define OFF_KW2F  1310720    // kw2 f16 B-frag order [10][7][64][8]: 71,680 B
#define OFF_PNW   1382400    // pointnet weights f16 frag order   :   229,376 B
#define OFF_KW1F  1611776    // kw1 f16 frag order [2][16][20][512]: 655,360 B
#define OFF_R     2267136    // R fp32 [2][256][256]              :   524,288 B
#define OFF_WGT   2791424    // weight fp32 [2][256]              :     2,048 B

// ============ prep: kw2 -> B-frag order; pn + kw1 weights -> B-frag order ============
// B-frag (mfma_f32_16x16x32_f16): lane l holds B[k][n] with n = nt*16 + (l&15),
// k = s*32 + (l>>4)*8 + e, e=0..7 contiguous -> one dwordx4 per lane at runtime.
__global__ __launch_bounds__(256) void k_prep(
    const float* __restrict__ kw2, const float* __restrict__ kw1,
    const float* __restrict__ pw0, const float* __restrict__ pw1,
    const float* __restrict__ pw2, const float* __restrict__ pw3,
    const float* __restrict__ pw4,
    _Float16* __restrict__ kw2ff, _Float16* __restrict__ pnw,
    _Float16* __restrict__ kw1f)
{
    int idx = blockIdx.x * 256 + threadIdx.x;
    if (idx < 35840) {                       // kw2ff [kc10][nt7][64][8]
        int e = idx & 7, lane = (idx >> 3) & 63, r = idx >> 9;   // r 0..69
        int nt = r % 7, kc = r / 7;
        int g = nt * 16 + (lane & 15);
        int k = kc * 32 + ((lane >> 4) << 3) + e;
        kw2ff[idx] = (_Float16)((g < H2 && k < H1) ? kw2[g * H1 + k] : 0.f);
        return;
    }
    int i = idx - 35840;
    if (i < 114688) {                        // pointnet frags
        const float* src; int K, NT, off;
        if      (i < 32768) { src = pw0; K = 512; NT = 4;  off = 0; }
        else if (i < 36864) { src = pw1; K = 64;  NT = 4;  off = 32768; }
        else if (i < 40960) { src = pw2; K = 64;  NT = 4;  off = 36864; }
        else if (i < 49152) { src = pw3; K = 64;  NT = 8;  off = 40960; }
        else                { src = pw4; K = 128; NT = 32; off = 49152; }
        int li = i - off;
        int e = li & 7, l = (li >> 3) & 63, r = li >> 9;
        int nt = r % NT, s = r / NT;
        int o = nt * 16 + (l & 15);
        int c = s * 32 + ((l >> 4) << 3) + e;
        pnw[i] = (_Float16)src[o * K + c];
        return;
    }
    i -= 114688;
    if (i < 327680) {                        // kw1 frags [half][s16][nt20][64][8]
        int e = i & 7, l = (i >> 3) & 63, r = i >> 9;     // r 0..639
        int nt = r % 20, s = (r / 20) & 15, half = r / 320;
        int h = nt * 16 + (l & 15);
        int c = s * 32 + ((l >> 4) << 3) + e;
        kw1f[i] = (_Float16)((h < H1) ? kw1[h * (2 * FDIM) + half * FDIM + c] : 0.f);
    }
}

// ============ Kernel A: first-layer GEMMs via MFMA, LDS-staged A, 4 waves/block ==========
#define XSTR 520
__global__ __launch_bounds__(256) void k_apart(
    const float* __restrict__ embA, const float* __restrict__ embB,
    const _Float16* __restrict__ kw1f, const float* __restrict__ kb1,
    _Float16* __restrict__ ap)
{
    const int ntile = blockIdx.x, jb = blockIdx.y;
    const int j = jb >> 1, b = jb & 1;
    const int n0 = ntile * 16;
    const int tid = threadIdx.x;
    const int wave = tid >> 6, lane = tid & 63;
    const int l15 = lane & 15, quad = lane >> 4;

    __shared__ __align__(16) _Float16 sX[16 * XSTR];

    const float* emb = ((j < 2) ? embA : embB) + b * FDIM * NPTS;
    {
        const int n = tid & 15, fp = tid >> 4;
        const float* src = emb + n0 + n;
        _Float16* dst = &sX[n * XSTR];
        #pragma unroll
        for (int i = 0; i < 16; ++i) {
            int f = 2 * fp + 32 * i;
            float e0 = src[(size_t)f * NPTS];
            float e1 = src[(size_t)(f + 1) * NPTS];
            half2v hv; hv.x = (_Float16)e0; hv.y = (_Float16)e1;
            *reinterpret_cast<half2v*>(&dst[f]) = hv;
        }
    }

    const _Float16* wf = kw1f + (size_t)(j & 1) * 163840;
    floatx4 acc[5];
    #pragma unroll
    for (int q = 0; q < 5; ++q) acc[q] = (floatx4){0.f, 0.f, 0.f, 0.f};

    __syncthreads();

    const _Float16* arow = &sX[l15 * XSTR + quad * 8];
    #pragma unroll 4
    for (int s = 0; s < 16; ++s) {
        half8 af = *reinterpret_cast<const half8*>(&arow[s * 32]);
        const _Float16* wrow = wf + ((size_t)(s * 20 + wave * 5) * 64 + lane) * 8;
        #pragma unroll
        for (int q = 0; q < 5; ++q) {
            half8 bf = *reinterpret_cast<const half8*>(wrow + q * 512);
            acc[q] = __builtin_amdgcn_mfma_f32_16x16x32_f16(af, bf, acc[q], 0, 0, 0);
        }
    }

    const bool addb = (j < 2);
    _Float16* apb = ap + (size_t)jb * NPTS * KP;
    #pragma unroll
    for (int q = 0; q < 5; ++q) {
        int nt = wave * 5 + q;
        int h = nt * 16 + l15;
        float bv = (addb && h < H1) ? kb1[h] : 0.f;
        #pragma unroll
        for (int r = 0; r < 4; ++r) {
            int n = n0 + quad * 4 + r;
            apb[(size_t)n * KP + h] = (_Float16)(acc[q][r] + bv);
        }
    }
}

// ============ Kernel B: fused pair tail via f16 MFMA — register A-frags, no K-loop barriers ====
#define SA_STR 328
__global__ __launch_bounds__(256, 2) void k_pair(
    const _Float16* __restrict__ ap, const _Float16* __restrict__ kw2ff,
    const float* __restrict__ kb2, const float* __restrict__ kw3,
    const float* __restrict__ kb3, float* __restrict__ R)
{
    const int mt = blockIdx.x, nt = blockIdx.y, b = blockIdx.z;
    const int m0 = mt * 16, n0 = nt * 8;
    __shared__ __align__(16) _Float16 sA[16 * SA_STR];
    __shared__ __align__(16) _Float16 sBT[2 * 10 * 64 * 8];
    __shared__ float sV[256];
    const int tid = threadIdx.x;
    const int wave = tid >> 6, lane = tid & 63;
    const int l15 = lane & 15, quad = lane >> 4;

    for (int idx = tid; idx < 640; idx += 256) {
        int row = idx / 40, col = (idx - row * 40) * 8;
        int t = row >> 3, r = row & 7;
        half8 v = *reinterpret_cast<const half8*>(
            &ap[(size_t)((t * 2 + b) * NPTS + n0 + r) * KP + col]);
        *reinterpret_cast<half8*>(&sA[row * SA_STR + col]) = v;
    }
    for (int idx = tid; idx < 1280; idx += 256) {
        int ln = idx & 63, kc = (idx >> 6) % 10, t = idx / 640;
        int j = t ? 2 : 3;
        half8 v = *reinterpret_cast<const half8*>(
            &ap[(size_t)((j * 2 + b) * NPTS + m0 + (ln & 15)) * KP + kc * 32 + ((ln >> 4) << 3)]);
        *reinterpret_cast<half8*>(&sBT[(size_t)idx * 8]) = v;
    }
    __syncthreads();

    const int tail = wave >> 1;
    const _Float16* sBTt = &sBT[(size_t)tail * 10 * 64 * 8 + (size_t)lane * 8];
    const _Float16* aRow0 = &sA[(size_t)(tail * 8 + (wave & 1) * 4) * SA_STR + quad * 8];
    const _Float16* kwf = kw2ff + (size_t)lane * 8;

    floatx4 acc[4][7];
    #pragma unroll
    for (int i = 0; i < 4; ++i)
        #pragma unroll
        for (int jj = 0; jj < 7; ++jj)
            acc[i][jj] = (floatx4){0.f, 0.f, 0.f, 0.f};

    for (int kc = 0; kc < 10; ++kc) {
        half8 bfrag = *reinterpret_cast<const half8*>(&sBTt[(size_t)kc * 64 * 8]);
        half8 af[4];
        #pragma unroll
        for (int i = 0; i < 4; ++i) {
            half8 av = *reinterpret_cast<const half8*>(&aRow0[i * SA_STR + kc * 32]);
            half8 s = av + bfrag;
            half8 rv;
            #pragma unroll
            for (int e = 0; e < 8; ++e)
                rv[e] = s[e] > (_Float16)0 ? s[e] : (_Float16)0;
            af[i] = rv;
        }
        #pragma unroll
        for (int jj = 0; jj < 7; ++jj) {
            half8 bw = *reinterpret_cast<const half8*>(&kwf[(size_t)(kc * 7 + jj) * 64 * 8]);
            #pragma unroll
            for (int i = 0; i < 4; ++i)
                acc[i][jj] = __builtin_amdgcn_mfma_f32_16x16x32_f16(af[i], bw, acc[i][jj], 0, 0, 0);
        }
    }

    float kw3v[7], kb2v[7];
    #pragma unroll
    for (int jj = 0; jj < 7; ++jj) {
        int g = jj * 16 + l15;
        kw3v[jj] = (g < H2) ? kw3[g] : 0.f;
        kb2v[jj] = (g < H2) ? kb2[g] : 0.f;
    }
    #pragma unroll
    for (int i = 0; i < 4; ++i) {
        float rv0 = 0.f, rv1 = 0.f, rv2 = 0.f, rv3 = 0.f;
        #pragma unroll
        for (int jj = 0; jj < 7; ++jj) {
            float w3 = kw3v[jj], b2 = kb2v[jj];
            rv0 = fmaf(w3, fmaxf(acc[i][jj][0] + b2, 0.f), rv0);
            rv1 = fmaf(w3, fmaxf(acc[i][jj][1] + b2, 0.f), rv1);
            rv2 = fmaf(w3, fmaxf(acc[i][jj][2] + b2, 0.f), rv2);
            rv3 = fmaf(w3, fmaxf(acc[i][jj][3] + b2, 0.f), rv3);
        }
        #pragma unroll
        for (int m = 1; m < 16; m <<= 1) {
            rv0 += __shfl_xor(rv0, m, 64);
            rv1 += __shfl_xor(rv1, m, 64);
            rv2 += __shfl_xor(rv2, m, 64);
            rv3 += __shfl_xor(rv3, m, 64);
        }
        if (l15 == 0) {
            int base = (wave * 4 + i) * 16 + quad * 4;
            sV[base + 0] = rv0; sV[base + 1] = rv1;
            sV[base + 2] = rv2; sV[base + 3] = rv3;
        }
    }
    __syncthreads();
    if (tid < 128) {
        float s = 0.5f * (sV[tid] + sV[128 + tid]) + kb3[0];
        float sp = fmaxf(s, 0.f) + log1pf(expf(-fabsf(s)));
        int n_l = tid >> 4, m_l = tid & 15;
        R[(size_t)(b * NPTS + n0 + n_l) * NPTS + m0 + m_l] = sp;
    }
}

// ============ PointNet via MFMA, 4 waves/block: layer N-tiles split across waves ============
// grid (16, 2), block 256: 16 points per block, emb tile staged to LDS once.
__global__ __launch_bounds__(256) void k_pn_mfma(
    const float* __restrict__ emb, const _Float16* __restrict__ pnw,
    const float* __restrict__ pb0, const float* __restrict__ pb1,
    const float* __restrict__ pb2, const float* __restrict__ pb3,
    const float* __restrict__ pb4, const float* __restrict__ headw,
    float* __restrict__ wgt)
{
    const int n0 = blockIdx.x * 16, b = blockIdx.y;
    const int tid = threadIdx.x;
    const int wave = tid >> 6, lane = tid & 63;
    const int l15 = lane & 15, quad = lane >> 4;
    __shared__ __align__(16) _Float16 sX[16 * XSTR];
    __shared__ __align__(16) _Float16 sH[16][136];
    __shared__ float sVp[4][16];

    // ---- stage emb[512 f][16 n] -> sX[n][f] f16 (coalesced 64B rows) ----
    {
        const int n = tid & 15, fp = tid >> 4;
        const float* src = emb + (size_t)b * FDIM * NPTS + n0 + n;
        _Float16* dst = &sX[n * XSTR];
        #pragma unroll
        for (int i = 0; i < 16; ++i) {
            int f = 2 * fp + 32 * i;
            float e0 = src[(size_t)f * NPTS];
            float e1 = src[(size_t)(f + 1) * NPTS];
            half2v hv; hv.x = (_Float16)e0; hv.y = (_Float16)e1;
            *reinterpret_cast<half2v*>(&dst[f]) = hv;
        }
    }
    __syncthreads();

    const _Float16* w0f = pnw;
    const _Float16* w1f = pnw + 32768;
    const _Float16* w2f = pnw + 36864;
    const _Float16* w3f = pnw + 40960;
    const _Float16* w4f = pnw + 49152;

    // ---- L0: 512 -> 64 ; wave w owns N-tile w ----
    {
        const _Float16* arow = &sX[l15 * XSTR + quad * 8];
        floatx4 acc = (floatx4){0.f, 0.f, 0.f, 0.f};
        #pragma unroll 4
        for (int s = 0; s < 16; ++s) {
            half8 af = *reinterpret_cast<const half8*>(&arow[s * 32]);
            half8 bf = *reinterpret_cast<const half8*>(w0f + ((size_t)(s * 4 + wave) * 64 + lane) * 8);
            acc = __builtin_amdgcn_mfma_f32_16x16x32_f16(af, bf, acc, 0, 0, 0);
        }
        int o = wave * 16 + l15;
        float bv = pb0[o];
        #pragma unroll
        for (int r = 0; r < 4; ++r)
            sH[quad * 4 + r][o] = (_Float16)fmaxf(acc[r] + bv, 0.f);
    }
    __syncthreads();

    // ---- L1, L2: 64 -> 64 ; wave w owns N-tile w ----
    const _Float16* wfs[2] = {w1f, w2f};
    const float* pbs[2] = {pb1, pb2};
    #pragma unroll
    for (int layer = 0; layer < 2; ++layer) {
        half8 a0 = *reinterpret_cast<const half8*>(&sH[l15][quad * 8]);
        half8 a1 = *reinterpret_cast<const half8*>(&sH[l15][32 + quad * 8]);
        half8 b0 = *reinterpret_cast<const half8*>(wfs[layer] + ((size_t)(wave) * 64 + lane) * 8);
        half8 b1 = *reinterpret_cast<const half8*>(wfs[layer] + ((size_t)(4 + wave) * 64 + lane) * 8);
        floatx4 ac = __builtin_amdgcn_mfma_f32_16x16x32_f16(a0, b0, (floatx4){0.f,0.f,0.f,0.f}, 0, 0, 0);
        ac = __builtin_amdgcn_mfma_f32_16x16x32_f16(a1, b1, ac, 0, 0, 0);
        __syncthreads();
        int o = wave * 16 + l15;
        float bv = pbs[layer][o];
        #pragma unroll
        for (int r = 0; r < 4; ++r)
            sH[quad * 4 + r][o] = (_Float16)fmaxf(ac[r] + bv, 0.f);
        __syncthreads();
    }

    // ---- L3: 64 -> 128 ; wave w owns N-tiles 2w, 2w+1 ----
    {
        half8 a0 = *reinterpret_cast<const half8*>(&sH[l15][quad * 8]);
        half8 a1 = *reinterpret_cast<const half8*>(&sH[l15][32 + quad * 8]);
        floatx4 ac[2];
        #pragma unroll
        for (int q = 0; q < 2; ++q) {
            int nt = 2 * wave + q;
            half8 b0 = *reinterpret_cast<const half8*>(w3f + ((size_t)nt * 64 + lane) * 8);
            half8 b1 = *reinterpret_cast<const half8*>(w3f + ((size_t)(8 + nt) * 64 + lane) * 8);
            ac[q] = __builtin_amdgcn_mfma_f32_16x16x32_f16(a0, b0, (floatx4){0.f,0.f,0.f,0.f}, 0, 0, 0);
            ac[q] = __builtin_amdgcn_mfma_f32_16x16x32_f16(a1, b1, ac[q], 0, 0, 0);
        }
        __syncthreads();
        #pragma unroll
        for (int q = 0; q < 2; ++q) {
            int o = (2 * wave + q) * 16 + l15;
            float bv = pb3[o];
            #pragma unroll
            for (int r = 0; r < 4; ++r)
                sH[quad * 4 + r][o] = (_Float16)fmaxf(ac[q][r] + bv, 0.f);
        }
        __syncthreads();
    }

    // ---- L4: 128 -> 512 + head ; wave w owns N-tiles 8w..8w+7 ----
    half8 a4[4];
    #pragma unroll
    for (int s = 0; s < 4; ++s)
        a4[s] = *reinterpret_cast<const half8*>(&sH[l15][s * 32 + quad * 8]);
    float ps0 = 0.f, ps1 = 0.f, ps2 = 0.f, ps3 = 0.f;
    #pragma unroll 2
    for (int q = 0; q < 8; ++q) {
        int nt = wave * 8 + q;
        floatx4 a = (floatx4){0.f, 0.f, 0.f, 0.f};
        #pragma unroll
        for (int s = 0; s < 4; ++s) {
            half8 bf = *reinterpret_cast<const half8*>(w4f + ((size_t)(s * 32 + nt) * 64 + lane) * 8);
            a = __builtin_amdgcn_mfma_f32_16x16x32_f16(a4[s], bf, a, 0, 0, 0);
        }
        int o = nt * 16 + l15;
        float hwv = headw[o], b4v = pb4[o];
        ps0 = fmaf(hwv, fmaxf(a[0] + b4v, 0.f), ps0);
        ps1 = fmaf(hwv, fmaxf(a[1] + b4v, 0.f), ps1);
        ps2 = fmaf(hwv, fmaxf(a[2] + b4v, 0.f), ps2);
        ps3 = fmaf(hwv, fmaxf(a[3] + b4v, 0.f), ps3);
    }
    #pragma unroll
    for (int m = 1; m < 16; m <<= 1) {
        ps0 += __shfl_xor(ps0, m, 64);
        ps1 += __shfl_xor(ps1, m, 64);
        ps2 += __shfl_xor(ps2, m, 64);
        ps3 += __shfl_xor(ps3, m, 64);
    }
    if (l15 == 0) {
        sVp[wave][quad * 4 + 0] = ps0;
        sVp[wave][quad * 4 + 1] = ps1;
        sVp[wave][quad * 4 + 2] = ps2;
        sVp[wave][quad * 4 + 3] = ps3;
    }
    __syncthreads();
    if (tid < 16) {
        float s = sVp[0][tid] + sVp[1][tid] + sVp[2][tid] + sVp[3][tid];
        wgt[(size_t)b * NPTS + n0 + tid] = s;
    }
}

// ============ fused multilateration setup + solve + epilogue ============
__global__ __launch_bounds__(256) void k_solve(
    const float* __restrict__ R, const float* __restrict__ anchor_pts,
    const float* __restrict__ action_pts, const float* __restrict__ weight,
    float* __restrict__ out)
{
    const int a0 = blockIdx.x * 32, b = blockIdx.y;
    __shared__ float apx[256], apy[256], apz[256], sq[256];
    __shared__ float red[256];
    __shared__ float mb[12];
    const int t = threadIdx.x;
    const float px = anchor_pts[b * 768 + t];
    const float py = anchor_pts[b * 768 + 256 + t];
    const float pz = anchor_pts[b * 768 + 512 + t];
    apx[t] = px; apy[t] = py; apz[t] = pz;
    sq[t] = px * px + py * py + pz * pz;
    float sums[9];
    {
        float vals[9] = {px, py, pz, px*px, px*py, px*pz, py*py, py*pz, pz*pz};
        #pragma unroll
        for (int k = 0; k < 9; ++k) {
            red[t] = vals[k]; __syncthreads();
            for (int s = 128; s > 0; s >>= 1) {
                if (t < s) red[t] += red[t + s];
                __syncthreads();
            }
            sums[k] = red[0]; __syncthreads();
        }
    }
    if (t == 0) {
        const float inv = 1.f / 256.f;
        float mx = sums[0]*inv, my = sums[1]*inv, mz = sums[2]*inv;
        float a_ = sums[3]*inv - mx*mx;
        float b_ = sums[4]*inv - mx*my;
        float c_ = sums[5]*inv - mx*mz;
        float d_ = sums[6]*inv - my*my;
        float e_ = sums[7]*inv - my*mz;
        float f_ = sums[8]*inv - mz*mz;
        float c00 = d_*f_ - e_*e_;
        float c01 = c_*e_ - b_*f_;
        float c02 = b_*e_ - c_*d_;
        float det = a_*c00 + b_*c01 + c_*c02;
        float id = 1.f / det;
        mb[0] = mx; mb[1] = my; mb[2] = mz;
        mb[3] = c00*id;  mb[4] = c01*id;             mb[5] = c02*id;
        mb[6] = c01*id;  mb[7] = (a_*f_ - c_*c_)*id; mb[8] = (b_*c_ - a_*e_)*id;
        mb[9] = c02*id;  mb[10] = (b_*c_ - a_*e_)*id; mb[11] = (a_*d_ - b_*b_)*id;
    }
    __syncthreads();
    const int ar = a0 + (t >> 3), l8 = t & 7;
    const float Pbx = mb[0], Pby = mb[1], Pbz = mb[2];
    const float* Rrow = R + (size_t)(b * NPTS + ar) * NPTS;
    float v0 = 0.f, v1 = 0.f, v2 = 0.f;
    #pragma unroll 4
    for (int k = 0; k < 32; ++k) {
        int n = l8 + (k << 3);
        float Rv = Rrow[n];
        float cc = sq[n] - Rv * Rv;
        v0 = fmaf(cc, apx[n] - Pbx, v0);
        v1 = fmaf(cc, apy[n] - Pby, v1);
        v2 = fmaf(cc, apz[n] - Pbz, v2);
    }
    #pragma unroll
    for (int m = 1; m < 8; m <<= 1) {
        v0 += __shfl_xor(v0, m, 64);
        v1 += __shfl_xor(v1, m, 64);
        v2 += __shfl_xor(v2, m, 64);
    }
    if (l8 == 0) {
        const float sc = 0.5f / 256.f;
        v0 *= sc; v1 *= sc; v2 *= sc;
        float p0 = mb[3]*v0 + mb[4]*v1 + mb[5]*v2;
        float p1 = mb[6]*v0 + mb[7]*v1 + mb[8]*v2;
        float p2 = mb[9]*v0 + mb[10]*v1 + mb[11]*v2;
        float f0 = p0 - action_pts[b * 768 + ar];
        float f1 = p1 - action_pts[b * 768 + 256 + ar];
        float f2 = p2 - action_pts[b * 768 + 512 + ar];
        float wv = weight[b * NPTS + ar];
        out[b * 1024 + ar]              = f0;
        out[b * 1024 + 256 + ar]        = f1;
        out[b * 1024 + 512 + ar]        = f2;
        out[b * 1024 + 768 + ar]        = wv;
        out[2048 + b * 768 + ar]        = f0;
        out[2048 + b * 768 + 256 + ar]  = f1;
        out[2048 + b * 768 + 512 + ar]  = f2;
        out[3584 + b * 768 + ar]        = p0;
        out[3584 + b * 768 + 256 + ar]  = p1;
        out[3584 + b * 768 + 512 + ar]  = p2;
    }
}

extern "C" void kernel_launch(void* const* d_in, const int* in_sizes, int n_in,
                              void* d_out, int out_size, void* d_ws, size_t ws_size,
                              hipStream_t stream)
{
    const float* embA       = (const float*)d_in[0];
    const float* embB       = (const float*)d_in[1];
    const float* action_pts = (const float*)d_in[2];
    const float* anchor_pts = (const float*)d_in[3];
    const float* kw1 = (const float*)d_in[4];
    const float* kb1 = (const float*)d_in[5];
    const float* kw2 = (const float*)d_in[6];
    const float* kb2 = (const float*)d_in[7];
    const float* kw3 = (const float*)d_in[8];
    const float* kb3 = (const float*)d_in[9];
    const float* pw0 = (const float*)d_in[10];
    const float* pb0 = (const float*)d_in[11];
    const float* pw1 = (const float*)d_in[12];
    const float* pb1 = (const float*)d_in[13];
    const float* pw2 = (const float*)d_in[14];
    const float* pb2 = (const float*)d_in[15];
    const float* pw3 = (const float*)d_in[16];
    const float* pb3 = (const float*)d_in[17];
    const float* pw4 = (const float*)d_in[18];
    const float* pb4 = (const float*)d_in[19];
    const float* headw = (const float*)d_in[20];
    char* wsb = (char*)d_ws;
    float* out = (float*)d_out;

    _Float16* ap    = (_Float16*)(wsb + OFF_AP);
    _Float16* kw2ff = (_Float16*)(wsb + OFF_KW2F);
    _Float16* pnw   = (_Float16*)(wsb + OFF_PNW);
    _Float16* kw1f  = (_Float16*)(wsb + OFF_KW1F);
    float*    R     = (float*)(wsb + OFF_R);
    float*    wgt   = (float*)(wsb + OFF_WGT);

    hipLaunchKernelGGL(k_prep, dim3(1868), dim3(256), 0, stream,
                       kw2, kw1, pw0, pw1, pw2, pw3, pw4, kw2ff, pnw, kw1f);
    hipLaunchKernelGGL(k_apart, dim3(16, 8), dim3(256), 0, stream,
                       embA, embB, kw1f, kb1, ap);
    hipLaunchKernelGGL(k_pn_mfma, dim3(16, 2), dim3(256), 0, stream,
                       embA, pnw, pb0, pb1, pb2, pb3, pb4, headw, wgt);
    hipLaunchKernelGGL(k_pair, dim3(16, 32, 2), dim3(256), 0, stream,
                       ap, kw2ff, kb2, kw3, kb3, R);
    hipLaunchKernelGGL(k_solve, dim3(8, 2), dim3(256), 0, stream,
                       R, anchor_pts, action_pts, wgt, out);
}